// Round 7
// baseline (4942.599 us; speedup 1.0000x reference)
//
#include <hip/hip_runtime.h>
#include <hip/hip_bf16.h>

#define N_NODES 50000
#define N_EDGES 800000
#define DIM 64
#define NB 391      // dst buckets of 128 nodes
#define NBLK 128    // hist/scatter chunks
#define CHUNK 6250  // N_EDGES / NBLK
#define CAP 4096    // LDS staging per bucket segment
#define NTILES 3125 // 50000/16 row tiles
#define NBLKS 1024  // persistent grid (4 blocks/CU x 256 CU)
#define NWAVES 4096
#define NH (NB * NBLK)  // 50048
#define SBH 196         // ceil(NH/256)

typedef __attribute__((ext_vector_type(8))) short bf16x8;
typedef __attribute__((ext_vector_type(4))) float f32x4;

__device__ __forceinline__ float bf2f(unsigned short u) {
  return __uint_as_float(((unsigned int)u) << 16);
}
__device__ __forceinline__ unsigned short f2bf(float f) {
  unsigned int x = __float_as_uint(f);
  unsigned int r = (x + 0x7fffu + ((x >> 16) & 1u)) >> 16;  // RNE
  return (unsigned short)r;
}
__device__ __forceinline__ int eidx_at(const int* __restrict__ p, int k, int i64) {
  return p[i64 ? (k << 1) : k];
}

// flags[0]=bf16 inputs, flags[1]=int64 indices, flags[2]=global barrier counter
__global__ void k_detect(const unsigned short* __restrict__ feat,
                         const unsigned int* __restrict__ eidx,
                         int* __restrict__ flags) {
  int lane = threadIdx.x;  // 64 threads
  float v = bf2f(feat[2 * lane]);
  bool big = !(fabsf(v) < 1000.0f);
  unsigned long long bb = __ballot(big);
  unsigned int w = eidx[2 * lane + 1];
  unsigned long long bz = __ballot(w == 0u);
  if (lane == 0) {
    flags[0] = (__popcll(bb) < 8) ? 1 : 0;
    flags[1] = (__popcll(bz) == 64) ? 1 : 0;
    flags[2] = 0;  // zero the mega-kernel's barrier counter
  }
}

// device-wide barrier: monotonic counter, release-arrive / acquire-spin.
// Correct per G16 (cross-XCD): threadfence + agent-scope atomics; all 1024
// blocks are co-resident by construction (launch_bounds(256,4), 18KB LDS).
__device__ __forceinline__ void gbar(int* cnt, int target) {
  __syncthreads();
  if (threadIdx.x == 0) {
    __threadfence();  // release my block's writes at device scope
    __hip_atomic_fetch_add(cnt, 1, __ATOMIC_RELEASE, __HIP_MEMORY_SCOPE_AGENT);
    while (__hip_atomic_load(cnt, __ATOMIC_ACQUIRE, __HIP_MEMORY_SCOPE_AGENT) < target)
      __builtin_amdgcn_s_sleep(8);
  }
  __syncthreads();
  __threadfence();  // invalidate stale cache lines before consuming remote writes
}

// ---- per-item helpers (verified bodies from R5) ----
__device__ __forceinline__ void gemm_item(
    const unsigned short* __restrict__ xh, const unsigned short* __restrict__ xl,
    const bf16x8* __restrict__ WH, const bf16x8* __restrict__ WL,
    const unsigned short* __restrict__ baf, int mat, int it, int lane,
    unsigned short* __restrict__ hb, float* __restrict__ ss,
    float* __restrict__ sd) {
  const int wtile = it >> 1;
  const int cbh = (it & 1) * 2;  // col-blocks {cbh, cbh+1}
  const int r16 = lane & 15;
  const int g4 = lane >> 4;
  const int row0 = wtile * 16;

  bf16x8 Bh[2][2], Bl[2][2];
#pragma unroll
  for (int c = 0; c < 2; ++c)
#pragma unroll
    for (int ks = 0; ks < 2; ++ks) {
      int fi = ((mat * 4 + cbh + c) * 2 + ks) * 64 + lane;
      Bh[c][ks] = WH[fi];
      Bl[c][ks] = WL[fi];
    }

  bf16x8 Ah[2], Al[2];
#pragma unroll
  for (int ks = 0; ks < 2; ++ks) {
    Ah[ks] = *(const bf16x8*)(xh + (row0 + r16) * DIM + 32 * ks + 8 * g4);
    Al[ks] = *(const bf16x8*)(xl + (row0 + r16) * DIM + 32 * ks + 8 * g4);
  }

  f32x4 acc[2];
#pragma unroll
  for (int c = 0; c < 2; ++c) {
    acc[c] = (f32x4){0.f, 0.f, 0.f, 0.f};
#pragma unroll
    for (int ks = 0; ks < 2; ++ks) {
      acc[c] = __builtin_amdgcn_mfma_f32_16x16x32_bf16(Ah[ks], Bh[c][ks], acc[c], 0, 0, 0);
      acc[c] = __builtin_amdgcn_mfma_f32_16x16x32_bf16(Al[ks], Bh[c][ks], acc[c], 0, 0, 0);
      acc[c] = __builtin_amdgcn_mfma_f32_16x16x32_bf16(Ah[ks], Bl[c][ks], acc[c], 0, 0, 0);
    }
  }

#pragma unroll
  for (int c = 0; c < 2; ++c)
#pragma unroll
    for (int reg = 0; reg < 4; ++reg)
      hb[(row0 + 4 * g4 + reg) * DIM + (cbh + c) * 16 + r16] = f2bf(acc[c][reg]);

  if (cbh == 0) {
    f32x4 acc2 = (f32x4){0.f, 0.f, 0.f, 0.f};
#pragma unroll
    for (int ks = 0; ks < 2; ++ks) {
      bf16x8 Ba = *(const bf16x8*)(baf + ((mat * 2 + ks) * 64 + lane) * 8);
      acc2 = __builtin_amdgcn_mfma_f32_16x16x32_bf16(Ah[ks], Ba, acc2, 0, 0, 0);
      acc2 = __builtin_amdgcn_mfma_f32_16x16x32_bf16(Al[ks], Ba, acc2, 0, 0, 0);
    }
#pragma unroll
    for (int reg = 0; reg < 4; ++reg) {
      float tmp = acc2[reg] + __shfl_xor(acc2[reg], 1);  // col pairs (0,1)/(2,3)
      int row = row0 + 4 * g4 + reg;
      if (r16 == 0) ss[row] = tmp;
      else if (r16 == 2) sd[row] = tmp;
    }
  }
}

__device__ __forceinline__ void quad_accum(const unsigned short* __restrict__ hb,
                                           const int2* __restrict__ lps, int cl,
                                           int quarter, int c16, float4& acc) {
  const int quads = (cl + 3) >> 2;
#pragma unroll 4
  for (int tt = 0; tt < quads; ++tt) {
    int j = 4 * tt + quarter;  // tail entries have p=0,s=0 -> contribute 0
    int2 pv = lps[j];          // LDS broadcast within quarter-wave
    float pj = __int_as_float(pv.x);
    int sj = pv.y;
    ushort4 hv = *(const ushort4*)(hb + sj * DIM + 4 * c16);
    acc.x = fmaf(pj, bf2f(hv.x), acc.x);
    acc.y = fmaf(pj, bf2f(hv.y), acc.y);
    acc.z = fmaf(pj, bf2f(hv.z), acc.z);
    acc.w = fmaf(pj, bf2f(hv.w), acc.w);
  }
}

__device__ __forceinline__ void agg_node(
    const unsigned short* __restrict__ hb, const float* __restrict__ ss,
    const float* __restrict__ sd, const int* __restrict__ rowp,
    const int* __restrict__ csr, unsigned short* __restrict__ outH,
    unsigned short* __restrict__ outL, void* __restrict__ out_final, int bf,
    int do_elu, int is_final, int node, int lane, int2* __restrict__ lpw) {
  const int quarter = lane >> 4;
  const int c16 = lane & 15;
  const int base = rowp[node];
  const int deg = rowp[node + 1] - base;
  const float sdn = sd[node];

  float4 acc = {0.f, 0.f, 0.f, 0.f};
  float z;
  if (deg <= 64) {
    int s = 0;
    float p = 0.f;
    if (lane < deg) {
      s = csr[base + lane];
      float t = ss[s] + sdn;
      t = (t >= 0.f) ? t : 0.2f * t;
      p = __expf(t);  // shift-invariant softmax, scores O(10): no max-sub needed
    }
    lpw[lane] = make_int2(__float_as_int(p), s);
    z = p;
    __builtin_amdgcn_wave_barrier();
    quad_accum(hb, lpw, deg, quarter, c16, acc);
    __builtin_amdgcn_wave_barrier();  // lps slot reused by next node in loop
#pragma unroll
    for (int off = 32; off > 0; off >>= 1) z += __shfl_xor(z, off);
  } else {
    z = 0.f;
    for (int c = 0; c < deg; c += 64) {
      int j = c + lane;
      float p = 0.f; int s = 0;
      if (j < deg) {
        s = csr[base + j];
        float sc = ss[s] + sdn;
        sc = (sc >= 0.f) ? sc : 0.2f * sc;
        p = __expf(sc);
      }
      lpw[lane] = make_int2(__float_as_int(p), s);
      __builtin_amdgcn_wave_barrier();
      z += p;
      const int cl = (deg - c < 64) ? (deg - c) : 64;
      quad_accum(hb, lpw, cl, quarter, c16, acc);
      __builtin_amdgcn_wave_barrier();
    }
#pragma unroll
    for (int off = 32; off > 0; off >>= 1) z += __shfl_xor(z, off);
  }

  acc.x += __shfl_xor(acc.x, 16);
  acc.y += __shfl_xor(acc.y, 16);
  acc.z += __shfl_xor(acc.z, 16);
  acc.w += __shfl_xor(acc.w, 16);
  acc.x += __shfl_xor(acc.x, 32);
  acc.y += __shfl_xor(acc.y, 32);
  acc.z += __shfl_xor(acc.z, 32);
  acc.w += __shfl_xor(acc.w, 32);

  float inv = 1.f / (z + 1e-16f);
  float ox = acc.x * inv, oy = acc.y * inv;
  float oz = acc.z * inv, ow = acc.w * inv;
  if (do_elu) {
    ox = (ox > 0.f) ? ox : expm1f(ox);
    oy = (oy > 0.f) ? oy : expm1f(oy);
    oz = (oz > 0.f) ? oz : expm1f(oz);
    ow = (ow > 0.f) ? ow : expm1f(ow);
  }
  if (quarter == 0) {
    int idx = node * DIM + 4 * c16;
    if (is_final) {
      if (bf) {
        ushort4 o4 = {f2bf(ox), f2bf(oy), f2bf(oz), f2bf(ow)};
        *(ushort4*)((unsigned short*)out_final + idx) = o4;
      } else {
        float4 o4 = {ox, oy, oz, ow};
        *(float4*)((float*)out_final + idx) = o4;
      }
    } else {
      ushort4 h4, l4;
      h4.x = f2bf(ox); l4.x = f2bf(ox - bf2f(h4.x));
      h4.y = f2bf(oy); l4.y = f2bf(oy - bf2f(h4.y));
      h4.z = f2bf(oz); l4.z = f2bf(oz - bf2f(h4.z));
      h4.w = f2bf(ow); l4.w = f2bf(ow - bf2f(h4.w));
      *(ushort4*)(outH + idx) = h4;
      *(ushort4*)(outL + idx) = l4;
    }
  }
}

// ---------- persistent mega-kernel: all phases, 21 device barriers ----------
__global__ __launch_bounds__(256, 4) void k_mega(
    const void* __restrict__ feat, const int* __restrict__ eidx,
    const void* __restrict__ W1, const void* __restrict__ A1s,
    const void* __restrict__ A1d, const void* __restrict__ W2,
    const void* __restrict__ A2s, const void* __restrict__ A2d,
    int* __restrict__ flags, unsigned short* __restrict__ xh0,
    unsigned short* __restrict__ xl0, unsigned short* __restrict__ xh1,
    unsigned short* __restrict__ xl1, unsigned short* __restrict__ hb,
    unsigned short* __restrict__ wfH, unsigned short* __restrict__ wfL,
    unsigned short* __restrict__ baf, int2* __restrict__ ebuf,
    float* __restrict__ ss, float* __restrict__ sd, int* __restrict__ csr,
    int* __restrict__ hist, int* __restrict__ hscan, int* __restrict__ bsum,
    int* __restrict__ rowp, void* __restrict__ out_final) {
  __shared__ __align__(16) int smem[4608];  // 18 KB, reused per phase
  const int tid = threadIdx.x;
  const int blk = blockIdx.x;
  const int lane = tid & 63;
  const int wid = tid >> 6;
  const int gw = blk * 4 + wid;
  int* cnt = flags + 2;
  int bt = 0;
  const int bf = flags[0];
  const int i64 = flags[1];

  // ======== P0: wprep (blk<8) || hist (blk<128) || split (all) ========
  if (blk < 8) {  // fragment prep for head-matrix b
    float* Wsh = (float*)smem;       // 4096
    float* was = Wsh + DIM * DIM;    // 64
    float* wad = was + DIM;          // 64
    const int b = blk;
    const void* Wv = (b < 4) ? W1 : W2;
    const void* av = (b < 4) ? A1s : A2s;
    const void* dv = (b < 4) ? A1d : A2d;
    const int hm = (b < 4) ? b : b - 4;
    for (int i = tid; i < DIM * DIM; i += 256)
      Wsh[i] = bf ? bf2f(((const unsigned short*)Wv)[hm * DIM * DIM + i])
                  : ((const float*)Wv)[hm * DIM * DIM + i];
    __syncthreads();
    if (tid < 128) {
      int k = tid & 63, isd = tid >> 6;
      const void* aptr = isd ? dv : av;
      float acc = 0.f;
      for (int c = 0; c < DIM; ++c) {
        float a = bf ? bf2f(((const unsigned short*)aptr)[hm * DIM + c])
                     : ((const float*)aptr)[hm * DIM + c];
        acc = fmaf(Wsh[k * DIM + c], a, acc);
      }
      (isd ? wad : was)[k] = acc;
    }
    __syncthreads();
    for (int idx = tid; idx < 512; idx += 256) {
      int ln = idx & 63, ks = (idx >> 6) & 1, cb = idx >> 7;
      int g4 = ln >> 4, r16 = ln & 15;
      int fo = (((b * 4 + cb) * 2 + ks) * 64 + ln) * 8;
#pragma unroll
      for (int j = 0; j < 8; ++j) {
        int k = 32 * ks + 8 * g4 + j;
        float w = Wsh[k * DIM + 16 * cb + r16];
        unsigned short hu = f2bf(w);
        wfH[fo + j] = hu;
        wfL[fo + j] = f2bf(w - bf2f(hu));
      }
    }
    for (int idx = tid; idx < 128; idx += 256) {
      int ln = idx & 63, ks = idx >> 6;
      int g4 = ln >> 4, r16 = ln & 15;
      int fo = ((b * 2 + ks) * 64 + ln) * 8;
#pragma unroll
      for (int j = 0; j < 8; ++j) {
        int k = 32 * ks + 8 * g4 + j;
        unsigned short u = 0;
        if (r16 < 4) {
          float w_ = (r16 < 2) ? was[k] : wad[k];
          unsigned short uh = f2bf(w_);
          u = (r16 & 1) ? f2bf(w_ - bf2f(uh)) : uh;
        }
        baf[fo + j] = u;
      }
    }
    __syncthreads();  // LDS handoff to hist section (blocks 0..7)
  }
  if (blk < NBLK) {  // degree histogram over chunk blk
    int* h = smem;
    for (int i = tid; i < NB; i += 256) h[i] = 0;
    __syncthreads();
    int lo = blk * CHUNK;
    for (int i = tid; i < CHUNK; i += 256) {
      int d = eidx_at(eidx, N_EDGES + lo + i, i64);
      atomicAdd(&h[d >> 7], 1);
    }
    __syncthreads();
    for (int i = tid; i < NB; i += 256) hist[i * NBLK + blk] = h[i];
  }
  // feature split x -> hi/lo bf16 (all blocks)
  for (int i = (blk * 256 + tid) * 4; i < N_NODES * DIM; i += NBLKS * 256 * 4) {
    if (bf) {
      ushort4 v = *(const ushort4*)((const unsigned short*)feat + i);
      *(ushort4*)(xh1 + i) = v;
      *(ushort4*)(xl1 + i) = make_ushort4(0, 0, 0, 0);
    } else {
      float4 f = *(const float4*)((const float*)feat + i);
      ushort4 h4, l4;
      h4.x = f2bf(f.x); l4.x = f2bf(f.x - bf2f(h4.x));
      h4.y = f2bf(f.y); l4.y = f2bf(f.y - bf2f(h4.y));
      h4.z = f2bf(f.z); l4.z = f2bf(f.z - bf2f(h4.z));
      h4.w = f2bf(f.w); l4.w = f2bf(f.w - bf2f(h4.w));
      *(ushort4*)(xh1 + i) = h4;
      *(ushort4*)(xl1 + i) = l4;
    }
  }
  bt += NBLKS; gbar(cnt, bt);

  // ======== P1: scan1 over NH ========
  if (blk < SBH) {
    int* sm = smem;
    int i = blk * 256 + tid;
    int v = (i < NH) ? hist[i] : 0;
    sm[tid] = v;
    __syncthreads();
    for (int off = 1; off < 256; off <<= 1) {
      int x = (tid >= off) ? sm[tid - off] : 0;
      __syncthreads();
      sm[tid] += x;
      __syncthreads();
    }
    if (i < NH) hscan[i] = sm[tid] - v;
    if (tid == 255) bsum[blk] = sm[tid];
  }
  bt += NBLKS; gbar(cnt, bt);

  // ======== P2: scan2 (block 0) ========
  if (blk == 0) {
    int* sm = smem;
    int v = (tid < SBH) ? bsum[tid] : 0;
    sm[tid] = v;
    __syncthreads();
    for (int off = 1; off < 256; off <<= 1) {
      int x = (tid >= off) ? sm[tid - off] : 0;
      __syncthreads();
      sm[tid] += x;
      __syncthreads();
    }
    if (tid < SBH) bsum[tid] = sm[tid] - v;
  }
  bt += NBLKS; gbar(cnt, bt);

  // ======== P3: scan3 ========
  if (blk < SBH) {
    int i = blk * 256 + tid;
    if (i < NH) hscan[i] += bsum[blk];
  }
  bt += NBLKS; gbar(cnt, bt);

  // ======== P4: scatter ========
  if (blk < NBLK) {
    int* cur = smem;
    for (int i = tid; i < NB; i += 256) cur[i] = hscan[i * NBLK + blk];
    __syncthreads();
    int lo = blk * CHUNK;
    for (int i = tid; i < CHUNK; i += 256) {
      int d = eidx_at(eidx, N_EDGES + lo + i, i64);
      int s = eidx_at(eidx, lo + i, i64);
      int pos = atomicAdd(&cur[d >> 7], 1);
      ebuf[pos] = make_int2(s, d);
    }
  }
  bt += NBLKS; gbar(cnt, bt);

  // ======== P5: place (rowp + CSR) ========
  if (blk < NB) {
    int* hcnt = smem;
    int* sm = smem + 128;
    int* cur = smem + 256;
    int* lcsr = smem + 384;  // CAP ints
    int lo = hscan[blk * NBLK];
    int hi = (blk + 1 < NB) ? hscan[(blk + 1) * NBLK] : N_EDGES;
    if (tid < 128) hcnt[tid] = 0;
    __syncthreads();
    for (int i = lo + tid; i < hi; i += 256) atomicAdd(&hcnt[ebuf[i].y & 127], 1);
    __syncthreads();
    int v = (tid < 128) ? hcnt[tid] : 0;
    if (tid < 128) sm[tid] = v;
    __syncthreads();
    for (int off = 1; off < 128; off <<= 1) {
      int x = (tid < 128 && tid >= off) ? sm[tid - off] : 0;
      __syncthreads();
      if (tid < 128) sm[tid] += x;
      __syncthreads();
    }
    int d0 = blk * 128;
    if (tid < 128) {
      int excl = sm[tid] - v;
      cur[tid] = excl;
      int d = d0 + tid;
      if (d < N_NODES) rowp[d] = lo + excl;
    }
    if (blk == NB - 1 && tid == 0) rowp[N_NODES] = N_EDGES;
    __syncthreads();
    int seg_sz = hi - lo;
    if (seg_sz <= CAP) {
      for (int i = lo + tid; i < hi; i += 256) {
        int2 pr = ebuf[i];
        int pos = atomicAdd(&cur[pr.y & 127], 1);
        lcsr[pos] = pr.x;
      }
      __syncthreads();
      for (int i = tid; i < seg_sz; i += 256) csr[lo + i] = lcsr[i];
    } else {
      for (int i = lo + tid; i < hi; i += 256) {
        int2 pr = ebuf[i];
        int pos = atomicAdd(&cur[pr.y & 127], 1);
        csr[lo + pos] = pr.x;
      }
    }
  }
  bt += NBLKS; gbar(cnt, bt);

  // ======== 8 layers: gemm phase | bar | agg phase | bar ========
  const bf16x8* WH = (const bf16x8*)wfH;
  const bf16x8* WL = (const bf16x8*)wfL;
  int2* lps = (int2*)smem;  // 4 waves x 64 int2
  for (int m = 0; m < 8; ++m) {
    const unsigned short* xh = (m & 1) ? xh0 : xh1;
    const unsigned short* xl = (m & 1) ? xl0 : xl1;
    unsigned short* oh = (m & 1) ? xh1 : xh0;
    unsigned short* ol = (m & 1) ? xl1 : xl0;

    for (int it = gw; it < 2 * NTILES; it += NWAVES)
      gemm_item(xh, xl, WH, WL, baf, m, it, lane, hb, ss, sd);
    bt += NBLKS; gbar(cnt, bt);

    const int do_elu = (m == 3 || m == 7);
    const int fin = (m == 7);
    for (int node = gw; node < N_NODES; node += NWAVES)
      agg_node(hb, ss, sd, rowp, csr, oh, ol, out_final, bf, do_elu, fin,
               node, lane, lps + wid * 64);
    if (m < 7) { bt += NBLKS; gbar(cnt, bt); }
  }
}

// ---------- launch ----------
extern "C" void kernel_launch(void* const* d_in, const int* in_sizes, int n_in,
                              void* d_out, int out_size, void* d_ws, size_t ws_size,
                              hipStream_t stream) {
  const void* feat = d_in[0];
  const int* eidx = (const int*)d_in[1];

  unsigned short* xh0 = (unsigned short*)d_ws;          // N*64 bf16
  unsigned short* xl0 = xh0 + N_NODES * DIM;
  unsigned short* xh1 = xl0 + N_NODES * DIM;
  unsigned short* xl1 = xh1 + N_NODES * DIM;
  unsigned short* hb  = xl1 + N_NODES * DIM;
  unsigned short* wfH = hb + N_NODES * DIM;             // 32768
  unsigned short* wfL = wfH + 32768;                    // 32768
  unsigned short* baf = wfL + 32768;                    // 8192
  int2* ebuf = (int2*)(baf + 8192);                     // E int2
  float* ssrc = (float*)(ebuf + N_EDGES);               // N
  float* sdst = ssrc + N_NODES;                         // N
  int* csr  = (int*)(sdst + N_NODES);                   // E
  int* hist = csr + N_EDGES;                            // NB*NBLK
  int* hscan = hist + NB * NBLK;                        // NB*NBLK
  int* bsum = hscan + NB * NBLK;                        // 256
  int* rowp = bsum + 256;                               // N+1
  int* flags = rowp + N_NODES + 1;                      // 4 (incl. barrier cnt)

  k_detect<<<1, 64, 0, stream>>>((const unsigned short*)feat,
                                 (const unsigned int*)eidx, flags);
  k_mega<<<NBLKS, 256, 0, stream>>>(feat, eidx, d_in[2], d_in[3], d_in[4],
                                    d_in[5], d_in[6], d_in[7], flags,
                                    xh0, xl0, xh1, xl1, hb, wfH, wfL, baf,
                                    ebuf, ssrc, sdst, csr, hist, hscan, bsum,
                                    rowp, d_out);
}

// Round 9
// 444.304 us; speedup vs baseline: 11.1244x; 11.1244x over previous
//
#include <hip/hip_runtime.h>
#include <hip/hip_bf16.h>

#define N_NODES 50000
#define N_EDGES 800000
#define DIM 64
#define NB 391      // dst buckets of 128 nodes: ceil(50000/128)
#define NBLK 128    // blocks in bucketize pass
#define CHUNK 6250  // N_EDGES / NBLK (exact)
#define CAP 4096    // LDS staging capacity per bucket segment (avg ~2048)
#define NTILES 3125 // 50000 / 16 row-tiles (exact)

typedef __attribute__((ext_vector_type(8))) short bf16x8;
typedef __attribute__((ext_vector_type(4))) float f32x4;

// ---------- helpers ----------
__device__ __forceinline__ float bf2f(unsigned short u) {
  return __uint_as_float(((unsigned int)u) << 16);
}
__device__ __forceinline__ unsigned short f2bf(float f) {
  unsigned int x = __float_as_uint(f);
  unsigned int r = (x + 0x7fffu + ((x >> 16) & 1u)) >> 16;  // RNE
  return (unsigned short)r;
}

// ---------- dtype detection (flags[0]=bf16 inputs, flags[1]=int64 indices) ----------
__global__ void k_detect(const unsigned short* __restrict__ feat,
                         const unsigned int* __restrict__ eidx,
                         int* __restrict__ flags) {
  int lane = threadIdx.x;  // 64 threads
  float v = bf2f(feat[2 * lane]);
  bool big = !(fabsf(v) < 1000.0f);
  unsigned long long bb = __ballot(big);
  unsigned int w = eidx[2 * lane + 1];
  unsigned long long bz = __ballot(w == 0u);
  if (lane == 0) {
    flags[0] = (__popcll(bb) < 8) ? 1 : 0;
    flags[1] = (__popcll(bz) == 64) ? 1 : 0;
  }
}

__device__ __forceinline__ int eidx_at(const int* __restrict__ p, int k, int i64) {
  return p[i64 ? (k << 1) : k];
}

// ---------- one-time fragment prep (R12, verified) ----------
__global__ __launch_bounds__(256) void k_wprep(
    const void* __restrict__ W1, const void* __restrict__ A1s,
    const void* __restrict__ A1d, const void* __restrict__ W2,
    const void* __restrict__ A2s, const void* __restrict__ A2d,
    const int* __restrict__ flags, unsigned short* __restrict__ wfH,
    unsigned short* __restrict__ wfL, unsigned short* __restrict__ baf) {
  __shared__ float Wsh[DIM * DIM];
  __shared__ float was[DIM], wad[DIM];
  const int b = blockIdx.x;  // head-matrix 0..7
  const int t = threadIdx.x;
  const int bf = flags[0];
  const void* Wv = (b < 4) ? W1 : W2;
  const void* av = (b < 4) ? A1s : A2s;
  const void* dv = (b < 4) ? A1d : A2d;
  const int hm = (b < 4) ? b : b - 4;
  for (int i = t; i < DIM * DIM; i += 256)
    Wsh[i] = bf ? bf2f(((const unsigned short*)Wv)[hm * DIM * DIM + i])
                : ((const float*)Wv)[hm * DIM * DIM + i];
  __syncthreads();
  if (t < 128) {
    int k = t & 63, isd = t >> 6;
    const void* aptr = isd ? dv : av;
    float acc = 0.f;
    for (int c = 0; c < DIM; ++c) {
      float a = bf ? bf2f(((const unsigned short*)aptr)[hm * DIM + c])
                   : ((const float*)aptr)[hm * DIM + c];
      acc = fmaf(Wsh[k * DIM + c], a, acc);
    }
    (isd ? wad : was)[k] = acc;
  }
  __syncthreads();
  // W fragments: value at (cb,ks,lane,j) = W[(32ks+8g4+j)*64 + 16cb+r16]
  for (int idx = t; idx < 512; idx += 256) {
    int lane = idx & 63, ks = (idx >> 6) & 1, cb = idx >> 7;
    int g4 = lane >> 4, r16 = lane & 15;
    int fo = (((b * 4 + cb) * 2 + ks) * 64 + lane) * 8;
#pragma unroll
    for (int j = 0; j < 8; ++j) {
      int k = 32 * ks + 8 * g4 + j;
      float w = Wsh[k * DIM + 16 * cb + r16];
      unsigned short hu = f2bf(w);
      wfH[fo + j] = hu;
      wfL[fo + j] = f2bf(w - bf2f(hu));
    }
  }
  // score fragments
  for (int idx = t; idx < 128; idx += 256) {
    int lane = idx & 63, ks = idx >> 6;
    int g4 = lane >> 4, r16 = lane & 15;
    int fo = ((b * 2 + ks) * 64 + lane) * 8;
#pragma unroll
    for (int j = 0; j < 8; ++j) {
      int k = 32 * ks + 8 * g4 + j;
      unsigned short u = 0;
      if (r16 < 4) {
        float w_ = (r16 < 2) ? was[k] : wad[k];
        unsigned short uh = f2bf(w_);
        u = (r16 & 1) ? f2bf(w_ - bf2f(uh)) : uh;
      }
      baf[fo + j] = u;
    }
  }
}

// ---------- layer-0 feature split: x -> hi/lo bf16 ----------
__global__ __launch_bounds__(256) void k_split(const void* __restrict__ feat,
                                               const int* __restrict__ flags,
                                               unsigned short* __restrict__ xh,
                                               unsigned short* __restrict__ xl) {
  int i = (blockIdx.x * 256 + threadIdx.x) * 4;
  if (i >= N_NODES * DIM) return;
  if (flags[0]) {
    ushort4 v = *(const ushort4*)((const unsigned short*)feat + i);
    *(ushort4*)(xh + i) = v;
    *(ushort4*)(xl + i) = make_ushort4(0, 0, 0, 0);
  } else {
    float4 f = *(const float4*)((const float*)feat + i);
    ushort4 h4, l4;
    h4.x = f2bf(f.x); l4.x = f2bf(f.x - bf2f(h4.x));
    h4.y = f2bf(f.y); l4.y = f2bf(f.y - bf2f(h4.y));
    h4.z = f2bf(f.z); l4.z = f2bf(f.z - bf2f(h4.z));
    h4.w = f2bf(f.w); l4.w = f2bf(f.w - bf2f(h4.w));
    *(ushort4*)(xh + i) = h4;
    *(ushort4*)(xl + i) = l4;
  }
}

// ---------- generalized scan (n <= 65536) ----------
__global__ void k_scan1(const int* __restrict__ in, int* __restrict__ out,
                        int* __restrict__ bsum, int n) {
  __shared__ int sm[256];
  int t = threadIdx.x, b = blockIdx.x, i = b * 256 + t;
  int v = (i < n) ? in[i] : 0;
  sm[t] = v;
  __syncthreads();
  for (int off = 1; off < 256; off <<= 1) {
    int x = (t >= off) ? sm[t - off] : 0;
    __syncthreads();
    sm[t] += x;
    __syncthreads();
  }
  if (i < n) out[i] = sm[t] - v;
  if (t == 255) bsum[b] = sm[t];
}

__global__ void k_scan2(int* __restrict__ bsum, int nb) {
  __shared__ int sm[256];
  int t = threadIdx.x;
  int v = (t < nb) ? bsum[t] : 0;
  sm[t] = v;
  __syncthreads();
  for (int off = 1; off < 256; off <<= 1) {
    int x = (t >= off) ? sm[t - off] : 0;
    __syncthreads();
    sm[t] += x;
    __syncthreads();
  }
  if (t < nb) bsum[t] = sm[t] - v;
}

__global__ void k_scan3(int* __restrict__ out, const int* __restrict__ bsum, int n) {
  int t = threadIdx.x, b = blockIdx.x, i = b * 256 + t;
  if (i < n) out[i] += bsum[b];
}

// ---------- bucketed CSR build ----------
__global__ __launch_bounds__(256) void k_hist1(const int* __restrict__ eidx,
                                               const int* __restrict__ flags,
                                               int* __restrict__ hist) {
  __shared__ int h[NB];
  int t = threadIdx.x, b = blockIdx.x;
  for (int i = t; i < NB; i += 256) h[i] = 0;
  __syncthreads();
  int i64 = flags[1];
  int lo = b * CHUNK;
  for (int i = t; i < CHUNK; i += 256) {
    int d = eidx_at(eidx, N_EDGES + lo + i, i64);
    atomicAdd(&h[d >> 7], 1);
  }
  __syncthreads();
  for (int i = t; i < NB; i += 256) hist[i * NBLK + b] = h[i];
}

__global__ __launch_bounds__(256) void k_scatter(const int* __restrict__ eidx,
                                                 const int* __restrict__ flags,
                                                 const int* __restrict__ hscan,
                                                 int2* __restrict__ ebuf) {
  __shared__ int cur[NB];
  int t = threadIdx.x, b = blockIdx.x;
  for (int i = t; i < NB; i += 256) cur[i] = hscan[i * NBLK + b];
  __syncthreads();
  int i64 = flags[1];
  int lo = b * CHUNK;
  for (int i = t; i < CHUNK; i += 256) {
    int d = eidx_at(eidx, N_EDGES + lo + i, i64);
    int s = eidx_at(eidx, lo + i, i64);
    int pos = atomicAdd(&cur[d >> 7], 1);
    ebuf[pos] = make_int2(s, d);
  }
}

__global__ __launch_bounds__(256) void k_place(const int2* __restrict__ ebuf,
                                               const int* __restrict__ hscan,
                                               int* __restrict__ rowp,
                                               int* __restrict__ csr) {
  __shared__ int hcnt[128];
  __shared__ int sm[128];
  __shared__ int cur[128];
  __shared__ int lcsr[CAP];
  int t = threadIdx.x, b = blockIdx.x;
  int lo = hscan[b * NBLK];
  int hi = (b + 1 < NB) ? hscan[(b + 1) * NBLK] : N_EDGES;
  if (t < 128) hcnt[t] = 0;
  __syncthreads();
  for (int i = lo + t; i < hi; i += 256) atomicAdd(&hcnt[ebuf[i].y & 127], 1);
  __syncthreads();
  int v = (t < 128) ? hcnt[t] : 0;
  if (t < 128) sm[t] = v;
  __syncthreads();
  for (int off = 1; off < 128; off <<= 1) {
    int x = (t < 128 && t >= off) ? sm[t - off] : 0;
    __syncthreads();
    if (t < 128) sm[t] += x;
    __syncthreads();
  }
  int d0 = b * 128;
  if (t < 128) {
    int excl = sm[t] - v;  // exclusive local prefix
    cur[t] = excl;
    int d = d0 + t;
    if (d < N_NODES) rowp[d] = lo + excl;
  }
  if (b == NB - 1 && t == 0) rowp[N_NODES] = N_EDGES;
  __syncthreads();
  int seg_sz = hi - lo;
  if (seg_sz <= CAP) {
    for (int i = lo + t; i < hi; i += 256) {
      int2 pr = ebuf[i];
      int pos = atomicAdd(&cur[pr.y & 127], 1);
      lcsr[pos] = pr.x;
    }
    __syncthreads();
    for (int i = t; i < seg_sz; i += 256) csr[lo + i] = lcsr[i];
  } else {  // overflow fallback
    for (int i = lo + t; i < hi; i += 256) {
      int2 pr = ebuf[i];
      int pos = atomicAdd(&cur[pr.y & 127], 1);
      csr[lo + pos] = pr.x;
    }
  }
}

// ---------- MFMA h = x@W (R12 structure, verified at 405-411 us total) ----------
__global__ __launch_bounds__(256) void k_gemm(
    const unsigned short* __restrict__ xh, const unsigned short* __restrict__ xl,
    const unsigned short* __restrict__ wfH, const unsigned short* __restrict__ wfL,
    const unsigned short* __restrict__ baf, int mat,
    unsigned short* __restrict__ hb, float* __restrict__ ss,
    float* __restrict__ sd) {
  const int lane = threadIdx.x & 63;
  const int w = blockIdx.x * 4 + (threadIdx.x >> 6);
  const int wtile = w >> 1;
  if (wtile >= NTILES) return;
  const int cbh = (w & 1) * 2;  // col-blocks {cbh, cbh+1}
  const int r16 = lane & 15;
  const int g4 = lane >> 4;
  const int row0 = wtile * 16;

  const bf16x8* WH = (const bf16x8*)wfH;
  const bf16x8* WL = (const bf16x8*)wfL;
  bf16x8 Bh[2][2], Bl[2][2];
#pragma unroll
  for (int c = 0; c < 2; ++c)
#pragma unroll
    for (int ks = 0; ks < 2; ++ks) {
      int fi = ((mat * 4 + cbh + c) * 2 + ks) * 64 + lane;
      Bh[c][ks] = WH[fi];
      Bl[c][ks] = WL[fi];
    }

  bf16x8 Ah[2], Al[2];
#pragma unroll
  for (int ks = 0; ks < 2; ++ks) {
    Ah[ks] = *(const bf16x8*)(xh + (row0 + r16) * DIM + 32 * ks + 8 * g4);
    Al[ks] = *(const bf16x8*)(xl + (row0 + r16) * DIM + 32 * ks + 8 * g4);
  }

  f32x4 acc[2];
#pragma unroll
  for (int c = 0; c < 2; ++c) {
    acc[c] = (f32x4){0.f, 0.f, 0.f, 0.f};
#pragma unroll
    for (int ks = 0; ks < 2; ++ks) {
      acc[c] = __builtin_amdgcn_mfma_f32_16x16x32_bf16(Ah[ks], Bh[c][ks], acc[c], 0, 0, 0);
      acc[c] = __builtin_amdgcn_mfma_f32_16x16x32_bf16(Al[ks], Bh[c][ks], acc[c], 0, 0, 0);
      acc[c] = __builtin_amdgcn_mfma_f32_16x16x32_bf16(Ah[ks], Bl[c][ks], acc[c], 0, 0, 0);
    }
  }

#pragma unroll
  for (int c = 0; c < 2; ++c)
#pragma unroll
    for (int reg = 0; reg < 4; ++reg)
      hb[(row0 + 4 * g4 + reg) * DIM + (cbh + c) * 16 + r16] = f2bf(acc[c][reg]);

  if (cbh == 0) {
    f32x4 acc2 = (f32x4){0.f, 0.f, 0.f, 0.f};
#pragma unroll
    for (int ks = 0; ks < 2; ++ks) {
      bf16x8 Ba = *(const bf16x8*)(baf + ((mat * 2 + ks) * 64 + lane) * 8);
      acc2 = __builtin_amdgcn_mfma_f32_16x16x32_bf16(Ah[ks], Ba, acc2, 0, 0, 0);
      acc2 = __builtin_amdgcn_mfma_f32_16x16x32_bf16(Al[ks], Ba, acc2, 0, 0, 0);
    }
#pragma unroll
    for (int reg = 0; reg < 4; ++reg) {
      float tmp = acc2[reg] + __shfl_xor(acc2[reg], 1);  // col pairs (0,1)/(2,3)
      int row = row0 + 4 * g4 + reg;
      if (r16 == 0) ss[row] = tmp;
      else if (r16 == 2) sd[row] = tmp;
    }
  }
}

// ---------- aggregation (R13: TWO nodes per wave for gather ILP) ----------
// Theory: one-node-per-wave agg has a single dependent chain
// csr -> ss-gather -> exp -> LDS -> h-gathers (~4 loads in flight). Two
// independent node chains per wave double in-flight loads; 25000 waves
// still = ~3 full-occupancy rounds.
__device__ __forceinline__ void quad_accum(const unsigned short* __restrict__ hb,
                                           const int2* __restrict__ lps, int cl,
                                           int quarter, int c16, float4& acc) {
  const int quads = (cl + 3) >> 2;
#pragma unroll 4
  for (int tt = 0; tt < quads; ++tt) {
    int j = 4 * tt + quarter;
    int2 pv = lps[j];
    float pj = __int_as_float(pv.x);
    int sj = pv.y;
    ushort4 hv = *(const ushort4*)(hb + sj * DIM + 4 * c16);
    acc.x = fmaf(pj, bf2f(hv.x), acc.x);
    acc.y = fmaf(pj, bf2f(hv.y), acc.y);
    acc.z = fmaf(pj, bf2f(hv.z), acc.z);
    acc.w = fmaf(pj, bf2f(hv.w), acc.w);
  }
}

// verified single-node path (R5) — used for the rare deg>64 case
__device__ __forceinline__ void agg_node_big(
    const unsigned short* __restrict__ hb, const float* __restrict__ ss,
    float sdn, int base, int deg, const int* __restrict__ csr, int lane,
    int quarter, int c16, int2* __restrict__ lpw, float4& acc, float& zo) {
  float z = 0.f;
  for (int c = 0; c < deg; c += 64) {
    int j = c + lane;
    float p = 0.f; int s = 0;
    if (j < deg) {
      s = csr[base + j];
      float sc = ss[s] + sdn;
      sc = (sc >= 0.f) ? sc : 0.2f * sc;
      p = __expf(sc);
    }
    lpw[lane] = make_int2(__float_as_int(p), s);
    __builtin_amdgcn_wave_barrier();
    z += p;
    const int cl = (deg - c < 64) ? (deg - c) : 64;
    quad_accum(hb, lpw, cl, quarter, c16, acc);
    __builtin_amdgcn_wave_barrier();
  }
#pragma unroll
  for (int off = 32; off > 0; off >>= 1) z += __shfl_xor(z, off);
  zo = z;
}

__device__ __forceinline__ void agg_epilogue(
    float4 acc, float z, int node, int quarter, int c16,
    unsigned short* __restrict__ outH, unsigned short* __restrict__ outL,
    void* __restrict__ out_final, int bf, int do_elu, int is_final) {
  acc.x += __shfl_xor(acc.x, 16);
  acc.y += __shfl_xor(acc.y, 16);
  acc.z += __shfl_xor(acc.z, 16);
  acc.w += __shfl_xor(acc.w, 16);
  acc.x += __shfl_xor(acc.x, 32);
  acc.y += __shfl_xor(acc.y, 32);
  acc.z += __shfl_xor(acc.z, 32);
  acc.w += __shfl_xor(acc.w, 32);
  float inv = 1.f / (z + 1e-16f);
  float ox = acc.x * inv, oy = acc.y * inv;
  float oz = acc.z * inv, ow = acc.w * inv;
  if (do_elu) {
    ox = (ox > 0.f) ? ox : expm1f(ox);
    oy = (oy > 0.f) ? oy : expm1f(oy);
    oz = (oz > 0.f) ? oz : expm1f(oz);
    ow = (ow > 0.f) ? ow : expm1f(ow);
  }
  if (quarter == 0) {
    int idx = node * DIM + 4 * c16;
    if (is_final) {
      if (bf) {
        ushort4 o4 = {f2bf(ox), f2bf(oy), f2bf(oz), f2bf(ow)};
        *(ushort4*)((unsigned short*)out_final + idx) = o4;
      } else {
        float4 o4 = {ox, oy, oz, ow};
        *(float4*)((float*)out_final + idx) = o4;
      }
    } else {
      ushort4 h4, l4;
      h4.x = f2bf(ox); l4.x = f2bf(ox - bf2f(h4.x));
      h4.y = f2bf(oy); l4.y = f2bf(oy - bf2f(h4.y));
      h4.z = f2bf(oz); l4.z = f2bf(oz - bf2f(h4.z));
      h4.w = f2bf(ow); l4.w = f2bf(ow - bf2f(h4.w));
      *(ushort4*)(outH + idx) = h4;
      *(ushort4*)(outL + idx) = l4;
    }
  }
}

__global__ __launch_bounds__(256) void k_agg(
    const unsigned short* __restrict__ hb, const float* __restrict__ ss,
    const float* __restrict__ sd, const int* __restrict__ rowp,
    const int* __restrict__ csr, unsigned short* __restrict__ outH,
    unsigned short* __restrict__ outL, void* __restrict__ out_final,
    const int* __restrict__ flags, int do_elu, int is_final) {
  __shared__ __align__(16) int2 lps[4][2][64];  // per wave: 2 node buffers
  const int lane = threadIdx.x & 63;
  const int quarter = lane >> 4;
  const int c16 = lane & 15;
  const int w = threadIdx.x >> 6;
  const int wv = blockIdx.x * 4 + w;  // 0..24999
  const int n0 = 2 * wv;
  const int n1 = 2 * wv + 1;
  const int bf = flags[0];

  // rowp[n0..n0+2]: one coalesced-ish read region
  const int base0 = rowp[n0];
  const int base1 = rowp[n1];
  const int end1 = rowp[n1 + 1];
  const int deg0 = base1 - base0;
  const int deg1 = end1 - base1;
  const float sdn0 = sd[n0];
  const float sdn1 = sd[n1];

  float4 acc0 = {0.f, 0.f, 0.f, 0.f};
  float4 acc1 = {0.f, 0.f, 0.f, 0.f};
  float z0, z1;

  if (deg0 <= 64 && deg1 <= 64) {
    // phase 1 for BOTH nodes (independent chains, loads overlap)
    int s0 = 0, s1 = 0;
    float p0 = 0.f, p1 = 0.f;
    if (lane < deg0) s0 = csr[base0 + lane];
    if (lane < deg1) s1 = csr[base1 + lane];
    if (lane < deg0) {
      float t = ss[s0] + sdn0;
      t = (t >= 0.f) ? t : 0.2f * t;
      p0 = __expf(t);
    }
    if (lane < deg1) {
      float t = ss[s1] + sdn1;
      t = (t >= 0.f) ? t : 0.2f * t;
      p1 = __expf(t);
    }
    lps[w][0][lane] = make_int2(__float_as_int(p0), s0);
    lps[w][1][lane] = make_int2(__float_as_int(p1), s1);
    z0 = p0; z1 = p1;
    __builtin_amdgcn_wave_barrier();
    // fused dual-node gather loop: 2 independent loads in flight / iter
    const int q0 = (deg0 + 3) >> 2;
    const int q1 = (deg1 + 3) >> 2;
    const int qm = (q0 > q1) ? q0 : q1;
    for (int tt = 0; tt < qm; ++tt) {
      int j = 4 * tt + quarter;
      if (tt < q0) {
        int2 pv = lps[w][0][j];
        float pj = __int_as_float(pv.x);
        ushort4 hv = *(const ushort4*)(hb + pv.y * DIM + 4 * c16);
        acc0.x = fmaf(pj, bf2f(hv.x), acc0.x);
        acc0.y = fmaf(pj, bf2f(hv.y), acc0.y);
        acc0.z = fmaf(pj, bf2f(hv.z), acc0.z);
        acc0.w = fmaf(pj, bf2f(hv.w), acc0.w);
      }
      if (tt < q1) {
        int2 pv = lps[w][1][j];
        float pj = __int_as_float(pv.x);
        ushort4 hv = *(const ushort4*)(hb + pv.y * DIM + 4 * c16);
        acc1.x = fmaf(pj, bf2f(hv.x), acc1.x);
        acc1.y = fmaf(pj, bf2f(hv.y), acc1.y);
        acc1.z = fmaf(pj, bf2f(hv.z), acc1.z);
        acc1.w = fmaf(pj, bf2f(hv.w), acc1.w);
      }
    }
    // z-reductions after gathers issued
#pragma unroll
    for (int off = 32; off > 0; off >>= 1) {
      z0 += __shfl_xor(z0, off);
      z1 += __shfl_xor(z1, off);
    }
  } else {
    // rare path: handle each node with the verified single-node loop
    if (deg0 <= 64) {
      int s0 = 0; float p0 = 0.f;
      if (lane < deg0) {
        s0 = csr[base0 + lane];
        float t = ss[s0] + sdn0;
        t = (t >= 0.f) ? t : 0.2f * t;
        p0 = __expf(t);
      }
      lps[w][0][lane] = make_int2(__float_as_int(p0), s0);
      z0 = p0;
      __builtin_amdgcn_wave_barrier();
      quad_accum(hb, &lps[w][0][0], deg0, quarter, c16, acc0);
      __builtin_amdgcn_wave_barrier();
#pragma unroll
      for (int off = 32; off > 0; off >>= 1) z0 += __shfl_xor(z0, off);
    } else {
      agg_node_big(hb, ss, sdn0, base0, deg0, csr, lane, quarter, c16,
                   &lps[w][0][0], acc0, z0);
    }
    if (deg1 <= 64) {
      int s1 = 0; float p1 = 0.f;
      if (lane < deg1) {
        s1 = csr[base1 + lane];
        float t = ss[s1] + sdn1;
        t = (t >= 0.f) ? t : 0.2f * t;
        p1 = __expf(t);
      }
      lps[w][1][lane] = make_int2(__float_as_int(p1), s1);
      z1 = p1;
      __builtin_amdgcn_wave_barrier();
      quad_accum(hb, &lps[w][1][0], deg1, quarter, c16, acc1);
      __builtin_amdgcn_wave_barrier();
#pragma unroll
      for (int off = 32; off > 0; off >>= 1) z1 += __shfl_xor(z1, off);
    } else {
      agg_node_big(hb, ss, sdn1, base1, deg1, csr, lane, quarter, c16,
                   &lps[w][1][0], acc1, z1);
    }
  }

  agg_epilogue(acc0, z0, n0, quarter, c16, outH, outL, out_final, bf, do_elu, is_final);
  agg_epilogue(acc1, z1, n1, quarter, c16, outH, outL, out_final, bf, do_elu, is_final);
}

// ---------- launch ----------
extern "C" void kernel_launch(void* const* d_in, const int* in_sizes, int n_in,
                              void* d_out, int out_size, void* d_ws, size_t ws_size,
                              hipStream_t stream) {
  const void* feat = d_in[0];
  const int* eidx = (const int*)d_in[1];

  unsigned short* xh0 = (unsigned short*)d_ws;          // N*64 bf16 (hi, buf0)
  unsigned short* xl0 = xh0 + N_NODES * DIM;            // N*64 bf16 (lo, buf0)
  unsigned short* xh1 = xl0 + N_NODES * DIM;            // N*64 bf16 (hi, buf1)
  unsigned short* xl1 = xh1 + N_NODES * DIM;            // N*64 bf16 (lo, buf1)
  unsigned short* hb  = xl1 + N_NODES * DIM;            // N*64 bf16
  unsigned short* wfH = hb + N_NODES * DIM;             // 32768
  unsigned short* wfL = wfH + 32768;                    // 32768
  unsigned short* baf = wfL + 32768;                    // 8192
  int2* ebuf = (int2*)(baf + 8192);                     // E int2
  float* ssrc = (float*)(ebuf + N_EDGES);               // N
  float* sdst = ssrc + N_NODES;                         // N
  int* csr  = (int*)(sdst + N_NODES);                   // E
  int* hist = csr + N_EDGES;                            // NB*NBLK
  int* hscan = hist + NB * NBLK;                        // NB*NBLK
  int* bsum = hscan + NB * NBLK;                        // 256
  int* rowp = bsum + 256;                               // N+1
  int* flags = rowp + N_NODES + 1;                      // 2

  const int NH = NB * NBLK;                 // 50048
  const int SBH = (NH + 255) / 256;         // 196

  k_detect<<<1, 64, 0, stream>>>((const unsigned short*)feat,
                                 (const unsigned int*)eidx, flags);
  k_wprep<<<8, 256, 0, stream>>>(d_in[2], d_in[3], d_in[4],
                                 d_in[5], d_in[6], d_in[7],
                                 flags, wfH, wfL, baf);
  k_split<<<(N_NODES * DIM / 4 + 255) / 256, 256, 0, stream>>>(feat, flags, xh1, xl1);
  k_hist1<<<NBLK, 256, 0, stream>>>(eidx, flags, hist);
  k_scan1<<<SBH, 256, 0, stream>>>(hist, hscan, bsum, NH);
  k_scan2<<<1, 256, 0, stream>>>(bsum, SBH);
  k_scan3<<<SBH, 256, 0, stream>>>(hscan, bsum, NH);
  k_scatter<<<NBLK, 256, 0, stream>>>(eidx, flags, hscan, ebuf);
  k_place<<<NB, 256, 0, stream>>>(ebuf, hscan, rowp, csr);

  const int GB = (2 * NTILES + 3) / 4;  // 6250 gemm waves, 2 waves/tile
  const int AB = N_NODES / 8;           // 6250 agg blocks: 4 waves x 2 nodes

  const unsigned short* xh = xh1;
  const unsigned short* xl = xl1;
  for (int i = 0; i < 8; ++i) {
    k_gemm<<<GB, 256, 0, stream>>>(xh, xl, wfH, wfL, baf, i, hb, ssrc, sdst);
    int elu = (i == 3 || i == 7) ? 1 : 0;
    int fin = (i == 7) ? 1 : 0;
    unsigned short* oh = (i & 1) ? xh1 : xh0;
    unsigned short* ol = (i & 1) ? xl1 : xl0;
    k_agg<<<AB, 256, 0, stream>>>(hb, ssrc, sdst, rowp, csr, oh, ol,
                                  d_out, flags, elu, fin);
    xh = oh; xl = ol;
  }
}

// Round 10
// 363.781 us; speedup vs baseline: 13.5867x; 1.2213x over previous
//
#include <hip/hip_runtime.h>
#include <hip/hip_bf16.h>

#define N_NODES 50000
#define N_EDGES 800000
#define DIM 64
#define NB 391      // dst buckets of 128 nodes: ceil(50000/128)
#define NBLK 128    // blocks in bucketize pass
#define CHUNK 6250  // N_EDGES / NBLK (exact)
#define CAP 4096    // LDS staging capacity per bucket segment (avg ~2048)
#define NTILES 3125 // 50000 / 16 row-tiles (exact)
#define FROWS 32    // fused kernel: rows (nodes) per block
#define FPAD 68     // LDS row stride (floats): 16B-aligned, 68%32=4 -> 2-way banks

typedef __attribute__((ext_vector_type(8))) short bf16x8;
typedef __attribute__((ext_vector_type(4))) float f32x4;

// ---------- helpers ----------
__device__ __forceinline__ float bf2f(unsigned short u) {
  return __uint_as_float(((unsigned int)u) << 16);
}
__device__ __forceinline__ unsigned short f2bf(float f) {
  unsigned int x = __float_as_uint(f);
  unsigned int r = (x + 0x7fffu + ((x >> 16) & 1u)) >> 16;  // RNE
  return (unsigned short)r;
}

// ---------- dtype detection (flags[0]=bf16 inputs, flags[1]=int64 indices) ----------
__global__ void k_detect(const unsigned short* __restrict__ feat,
                         const unsigned int* __restrict__ eidx,
                         int* __restrict__ flags) {
  int lane = threadIdx.x;  // 64 threads
  float v = bf2f(feat[2 * lane]);
  bool big = !(fabsf(v) < 1000.0f);
  unsigned long long bb = __ballot(big);
  unsigned int w = eidx[2 * lane + 1];
  unsigned long long bz = __ballot(w == 0u);
  if (lane == 0) {
    flags[0] = (__popcll(bb) < 8) ? 1 : 0;
    flags[1] = (__popcll(bz) == 64) ? 1 : 0;
  }
}

__device__ __forceinline__ int eidx_at(const int* __restrict__ p, int k, int i64) {
  return p[i64 ? (k << 1) : k];
}

// ---------- one-time fragment prep (R12, verified) ----------
__global__ __launch_bounds__(256) void k_wprep(
    const void* __restrict__ W1, const void* __restrict__ A1s,
    const void* __restrict__ A1d, const void* __restrict__ W2,
    const void* __restrict__ A2s, const void* __restrict__ A2d,
    const int* __restrict__ flags, unsigned short* __restrict__ wfH,
    unsigned short* __restrict__ wfL, unsigned short* __restrict__ baf) {
  __shared__ float Wsh[DIM * DIM];
  __shared__ float was[DIM], wad[DIM];
  const int b = blockIdx.x;  // head-matrix 0..7
  const int t = threadIdx.x;
  const int bf = flags[0];
  const void* Wv = (b < 4) ? W1 : W2;
  const void* av = (b < 4) ? A1s : A2s;
  const void* dv = (b < 4) ? A1d : A2d;
  const int hm = (b < 4) ? b : b - 4;
  for (int i = t; i < DIM * DIM; i += 256)
    Wsh[i] = bf ? bf2f(((const unsigned short*)Wv)[hm * DIM * DIM + i])
                : ((const float*)Wv)[hm * DIM * DIM + i];
  __syncthreads();
  if (t < 128) {
    int k = t & 63, isd = t >> 6;
    const void* aptr = isd ? dv : av;
    float acc = 0.f;
    for (int c = 0; c < DIM; ++c) {
      float a = bf ? bf2f(((const unsigned short*)aptr)[hm * DIM + c])
                   : ((const float*)aptr)[hm * DIM + c];
      acc = fmaf(Wsh[k * DIM + c], a, acc);
    }
    (isd ? wad : was)[k] = acc;
  }
  __syncthreads();
  // W fragments: value at (cb,ks,lane,j) = W[(32ks+8g4+j)*64 + 16cb+r16]
  for (int idx = t; idx < 512; idx += 256) {
    int lane = idx & 63, ks = (idx >> 6) & 1, cb = idx >> 7;
    int g4 = lane >> 4, r16 = lane & 15;
    int fo = (((b * 4 + cb) * 2 + ks) * 64 + lane) * 8;
#pragma unroll
    for (int j = 0; j < 8; ++j) {
      int k = 32 * ks + 8 * g4 + j;
      float w = Wsh[k * DIM + 16 * cb + r16];
      unsigned short hu = f2bf(w);
      wfH[fo + j] = hu;
      wfL[fo + j] = f2bf(w - bf2f(hu));
    }
  }
  // score fragments
  for (int idx = t; idx < 128; idx += 256) {
    int lane = idx & 63, ks = idx >> 6;
    int g4 = lane >> 4, r16 = lane & 15;
    int fo = ((b * 2 + ks) * 64 + lane) * 8;
#pragma unroll
    for (int j = 0; j < 8; ++j) {
      int k = 32 * ks + 8 * g4 + j;
      unsigned short u = 0;
      if (r16 < 4) {
        float w_ = (r16 < 2) ? was[k] : wad[k];
        unsigned short uh = f2bf(w_);
        u = (r16 & 1) ? f2bf(w_ - bf2f(uh)) : uh;
      }
      baf[fo + j] = u;
    }
  }
}

// ---------- layer-0 feature split: x -> hi/lo bf16 ----------
__global__ __launch_bounds__(256) void k_split(const void* __restrict__ feat,
                                               const int* __restrict__ flags,
                                               unsigned short* __restrict__ xh,
                                               unsigned short* __restrict__ xl) {
  int i = (blockIdx.x * 256 + threadIdx.x) * 4;
  if (i >= N_NODES * DIM) return;
  if (flags[0]) {
    ushort4 v = *(const ushort4*)((const unsigned short*)feat + i);
    *(ushort4*)(xh + i) = v;
    *(ushort4*)(xl + i) = make_ushort4(0, 0, 0, 0);
  } else {
    float4 f = *(const float4*)((const float*)feat + i);
    ushort4 h4, l4;
    h4.x = f2bf(f.x); l4.x = f2bf(f.x - bf2f(h4.x));
    h4.y = f2bf(f.y); l4.y = f2bf(f.y - bf2f(h4.y));
    h4.z = f2bf(f.z); l4.z = f2bf(f.z - bf2f(h4.z));
    h4.w = f2bf(f.w); l4.w = f2bf(f.w - bf2f(h4.w));
    *(ushort4*)(xh + i) = h4;
    *(ushort4*)(xl + i) = l4;
  }
}

// ---------- generalized scan (n <= 65536) ----------
__global__ void k_scan1(const int* __restrict__ in, int* __restrict__ out,
                        int* __restrict__ bsum, int n) {
  __shared__ int sm[256];
  int t = threadIdx.x, b = blockIdx.x, i = b * 256 + t;
  int v = (i < n) ? in[i] : 0;
  sm[t] = v;
  __syncthreads();
  for (int off = 1; off < 256; off <<= 1) {
    int x = (t >= off) ? sm[t - off] : 0;
    __syncthreads();
    sm[t] += x;
    __syncthreads();
  }
  if (i < n) out[i] = sm[t] - v;
  if (t == 255) bsum[b] = sm[t];
}

__global__ void k_scan2(int* __restrict__ bsum, int nb) {
  __shared__ int sm[256];
  int t = threadIdx.x;
  int v = (t < nb) ? bsum[t] : 0;
  sm[t] = v;
  __syncthreads();
  for (int off = 1; off < 256; off <<= 1) {
    int x = (t >= off) ? sm[t - off] : 0;
    __syncthreads();
    sm[t] += x;
    __syncthreads();
  }
  if (t < nb) bsum[t] = sm[t] - v;
}

__global__ void k_scan3(int* __restrict__ out, const int* __restrict__ bsum, int n) {
  int t = threadIdx.x, b = blockIdx.x, i = b * 256 + t;
  if (i < n) out[i] += bsum[b];
}

// ---------- bucketed CSR build ----------
__global__ __launch_bounds__(256) void k_hist1(const int* __restrict__ eidx,
                                               const int* __restrict__ flags,
                                               int* __restrict__ hist) {
  __shared__ int h[NB];
  int t = threadIdx.x, b = blockIdx.x;
  for (int i = t; i < NB; i += 256) h[i] = 0;
  __syncthreads();
  int i64 = flags[1];
  int lo = b * CHUNK;
  for (int i = t; i < CHUNK; i += 256) {
    int d = eidx_at(eidx, N_EDGES + lo + i, i64);
    atomicAdd(&h[d >> 7], 1);
  }
  __syncthreads();
  for (int i = t; i < NB; i += 256) hist[i * NBLK + b] = h[i];
}

__global__ __launch_bounds__(256) void k_scatter(const int* __restrict__ eidx,
                                                 const int* __restrict__ flags,
                                                 const int* __restrict__ hscan,
                                                 int2* __restrict__ ebuf) {
  __shared__ int cur[NB];
  int t = threadIdx.x, b = blockIdx.x;
  for (int i = t; i < NB; i += 256) cur[i] = hscan[i * NBLK + b];
  __syncthreads();
  int i64 = flags[1];
  int lo = b * CHUNK;
  for (int i = t; i < CHUNK; i += 256) {
    int d = eidx_at(eidx, N_EDGES + lo + i, i64);
    int s = eidx_at(eidx, lo + i, i64);
    int pos = atomicAdd(&cur[d >> 7], 1);
    ebuf[pos] = make_int2(s, d);
  }
}

__global__ __launch_bounds__(256) void k_place(const int2* __restrict__ ebuf,
                                               const int* __restrict__ hscan,
                                               int* __restrict__ rowp,
                                               int* __restrict__ csr) {
  __shared__ int hcnt[128];
  __shared__ int sm[128];
  __shared__ int cur[128];
  __shared__ int lcsr[CAP];
  int t = threadIdx.x, b = blockIdx.x;
  int lo = hscan[b * NBLK];
  int hi = (b + 1 < NB) ? hscan[(b + 1) * NBLK] : N_EDGES;
  if (t < 128) hcnt[t] = 0;
  __syncthreads();
  for (int i = lo + t; i < hi; i += 256) atomicAdd(&hcnt[ebuf[i].y & 127], 1);
  __syncthreads();
  int v = (t < 128) ? hcnt[t] : 0;
  if (t < 128) sm[t] = v;
  __syncthreads();
  for (int off = 1; off < 128; off <<= 1) {
    int x = (t < 128 && t >= off) ? sm[t - off] : 0;
    __syncthreads();
    if (t < 128) sm[t] += x;
    __syncthreads();
  }
  int d0 = b * 128;
  if (t < 128) {
    int excl = sm[t] - v;  // exclusive local prefix
    cur[t] = excl;
    int d = d0 + t;
    if (d < N_NODES) rowp[d] = lo + excl;
  }
  if (b == NB - 1 && t == 0) rowp[N_NODES] = N_EDGES;
  __syncthreads();
  int seg_sz = hi - lo;
  if (seg_sz <= CAP) {
    for (int i = lo + t; i < hi; i += 256) {
      int2 pr = ebuf[i];
      int pos = atomicAdd(&cur[pr.y & 127], 1);
      lcsr[pos] = pr.x;
    }
    __syncthreads();
    for (int i = t; i < seg_sz; i += 256) csr[lo + i] = lcsr[i];
  } else {  // overflow fallback
    for (int i = lo + t; i < hi; i += 256) {
      int2 pr = ebuf[i];
      int pos = atomicAdd(&cur[pr.y & 127], 1);
      csr[lo + pos] = pr.x;
    }
  }
}

// ---------- MFMA h = x@W (R12 structure; layer-0 only) ----------
__global__ __launch_bounds__(256) void k_gemm(
    const unsigned short* __restrict__ xh, const unsigned short* __restrict__ xl,
    const unsigned short* __restrict__ wfH, const unsigned short* __restrict__ wfL,
    const unsigned short* __restrict__ baf, int mat,
    unsigned short* __restrict__ hb, float* __restrict__ ss,
    float* __restrict__ sd) {
  const int lane = threadIdx.x & 63;
  const int w = blockIdx.x * 4 + (threadIdx.x >> 6);
  const int wtile = w >> 1;
  if (wtile >= NTILES) return;
  const int cbh = (w & 1) * 2;  // col-blocks {cbh, cbh+1}
  const int r16 = lane & 15;
  const int g4 = lane >> 4;
  const int row0 = wtile * 16;

  const bf16x8* WH = (const bf16x8*)wfH;
  const bf16x8* WL = (const bf16x8*)wfL;
  bf16x8 Bh[2][2], Bl[2][2];
#pragma unroll
  for (int c = 0; c < 2; ++c)
#pragma unroll
    for (int ks = 0; ks < 2; ++ks) {
      int fi = ((mat * 4 + cbh + c) * 2 + ks) * 64 + lane;
      Bh[c][ks] = WH[fi];
      Bl[c][ks] = WL[fi];
    }

  bf16x8 Ah[2], Al[2];
#pragma unroll
  for (int ks = 0; ks < 2; ++ks) {
    Ah[ks] = *(const bf16x8*)(xh + (row0 + r16) * DIM + 32 * ks + 8 * g4);
    Al[ks] = *(const bf16x8*)(xl + (row0 + r16) * DIM + 32 * ks + 8 * g4);
  }

  f32x4 acc[2];
#pragma unroll
  for (int c = 0; c < 2; ++c) {
    acc[c] = (f32x4){0.f, 0.f, 0.f, 0.f};
#pragma unroll
    for (int ks = 0; ks < 2; ++ks) {
      acc[c] = __builtin_amdgcn_mfma_f32_16x16x32_bf16(Ah[ks], Bh[c][ks], acc[c], 0, 0, 0);
      acc[c] = __builtin_amdgcn_mfma_f32_16x16x32_bf16(Al[ks], Bh[c][ks], acc[c], 0, 0, 0);
      acc[c] = __builtin_amdgcn_mfma_f32_16x16x32_bf16(Ah[ks], Bl[c][ks], acc[c], 0, 0, 0);
    }
  }

#pragma unroll
  for (int c = 0; c < 2; ++c)
#pragma unroll
    for (int reg = 0; reg < 4; ++reg)
      hb[(row0 + 4 * g4 + reg) * DIM + (cbh + c) * 16 + r16] = f2bf(acc[c][reg]);

  if (cbh == 0) {
    f32x4 acc2 = (f32x4){0.f, 0.f, 0.f, 0.f};
#pragma unroll
    for (int ks = 0; ks < 2; ++ks) {
      bf16x8 Ba = *(const bf16x8*)(baf + ((mat * 2 + ks) * 64 + lane) * 8);
      acc2 = __builtin_amdgcn_mfma_f32_16x16x32_bf16(Ah[ks], Ba, acc2, 0, 0, 0);
      acc2 = __builtin_amdgcn_mfma_f32_16x16x32_bf16(Al[ks], Ba, acc2, 0, 0, 0);
    }
#pragma unroll
    for (int reg = 0; reg < 4; ++reg) {
      float tmp = acc2[reg] + __shfl_xor(acc2[reg], 1);  // col pairs (0,1)/(2,3)
      int row = row0 + 4 * g4 + reg;
      if (r16 == 0) ss[row] = tmp;
      else if (r16 == 2) sd[row] = tmp;
    }
  }
}

// ---------- shared agg pieces (R5-verified) ----------
__device__ __forceinline__ void quad_accum(const unsigned short* __restrict__ hb,
                                           const int2* __restrict__ lps, int cl,
                                           int quarter, int c16, float4& acc) {
  const int quads = (cl + 3) >> 2;
#pragma unroll 4
  for (int tt = 0; tt < quads; ++tt) {
    int j = 4 * tt + quarter;  // tail entries have p=0,s=0 -> contribute 0
    int2 pv = lps[j];          // LDS broadcast within quarter-wave
    float pj = __int_as_float(pv.x);
    int sj = pv.y;
    ushort4 hv = *(const ushort4*)(hb + sj * DIM + 4 * c16);
    acc.x = fmaf(pj, bf2f(hv.x), acc.x);
    acc.y = fmaf(pj, bf2f(hv.y), acc.y);
    acc.z = fmaf(pj, bf2f(hv.z), acc.z);
    acc.w = fmaf(pj, bf2f(hv.w), acc.w);
  }
}

__device__ __forceinline__ void agg_node_big(
    const unsigned short* __restrict__ hb, const float* __restrict__ ss,
    float sdn, int base, int deg, const int* __restrict__ csr, int lane,
    int quarter, int c16, int2* __restrict__ lpw, float4& acc, float& zo) {
  float z = 0.f;
  for (int c = 0; c < deg; c += 64) {
    int j = c + lane;
    float p = 0.f; int s = 0;
    if (j < deg) {
      s = csr[base + j];
      float sc = ss[s] + sdn;
      sc = (sc >= 0.f) ? sc : 0.2f * sc;
      p = __expf(sc);
    }
    lpw[lane] = make_int2(__float_as_int(p), s);
    __builtin_amdgcn_wave_barrier();
    z += p;
    const int cl = (deg - c < 64) ? (deg - c) : 64;
    quad_accum(hb, lpw, cl, quarter, c16, acc);
    __builtin_amdgcn_wave_barrier();
  }
#pragma unroll
  for (int off = 32; off > 0; off >>= 1) z += __shfl_xor(z, off);
  zo = z;
}

// computes softmax-weighted aggregate for `node` into (ox..ow) on all lanes
// (lane's c16 selects cols 4c16..4c16+3). elu applied if do_elu.
__device__ __forceinline__ void agg_core(
    const unsigned short* __restrict__ hb, const float* __restrict__ ss,
    const float* __restrict__ sd, const int* __restrict__ rowp,
    const int* __restrict__ csr, int node, int lane, int quarter, int c16,
    int do_elu, int2* __restrict__ lpw, float& ox, float& oy, float& oz,
    float& ow) {
  const int base = rowp[node];
  const int deg = rowp[node + 1] - base;
  const float sdn = sd[node];
  float4 acc = {0.f, 0.f, 0.f, 0.f};
  float z;
  if (deg <= 64) {
    int s = 0;
    float p = 0.f;
    if (lane < deg) {
      s = csr[base + lane];
      float t = ss[s] + sdn;
      t = (t >= 0.f) ? t : 0.2f * t;
      p = __expf(t);  // shift-invariant softmax, scores O(10)
    }
    lpw[lane] = make_int2(__float_as_int(p), s);
    z = p;
    __builtin_amdgcn_wave_barrier();
    quad_accum(hb, lpw, deg, quarter, c16, acc);
    __builtin_amdgcn_wave_barrier();  // lpw reused by caller's next node
#pragma unroll
    for (int off = 32; off > 0; off >>= 1) z += __shfl_xor(z, off);
  } else {
    agg_node_big(hb, ss, sdn, base, deg, csr, lane, quarter, c16, lpw, acc, z);
  }
  acc.x += __shfl_xor(acc.x, 16);
  acc.y += __shfl_xor(acc.y, 16);
  acc.z += __shfl_xor(acc.z, 16);
  acc.w += __shfl_xor(acc.w, 16);
  acc.x += __shfl_xor(acc.x, 32);
  acc.y += __shfl_xor(acc.y, 32);
  acc.z += __shfl_xor(acc.z, 32);
  acc.w += __shfl_xor(acc.w, 32);
  float inv = 1.f / (z + 1e-16f);
  ox = acc.x * inv; oy = acc.y * inv;
  oz = acc.z * inv; ow = acc.w * inv;
  if (do_elu) {
    ox = (ox > 0.f) ? ox : expm1f(ox);
    oy = (oy > 0.f) ? oy : expm1f(oy);
    oz = (oz > 0.f) ? oz : expm1f(oz);
    ow = (ow > 0.f) ? ow : expm1f(ow);
  }
}

// ---------- R14: fused agg(layer i) -> gemm(layer i+1), row-local, no device sync ----------
// 512 thr = 8 waves. Each wave aggs 4 nodes into a [32][FPAD] fp32 LDS tile,
// __syncthreads, then wave w does col-block (w&3) of row-tile (w>>2) via MFMA
// (A split hi/lo in-register from fp32 LDS — identical arithmetic to the old
// memory hi/lo round-trip). Eliminates xh/xl intermediate + 7 dispatches.
__global__ __launch_bounds__(512) void k_fused(
    const unsigned short* __restrict__ hb_in, const float* __restrict__ ss_in,
    const float* __restrict__ sd_in, const int* __restrict__ rowp,
    const int* __restrict__ csr, const unsigned short* __restrict__ wfH,
    const unsigned short* __restrict__ wfL, const unsigned short* __restrict__ baf,
    int mat, int do_elu, unsigned short* __restrict__ hb_out,
    float* __restrict__ ss_out, float* __restrict__ sd_out) {
  __shared__ float outT[FROWS][FPAD];
  __shared__ __align__(16) int2 lps[8][64];
  const int tid = threadIdx.x;
  const int lane = tid & 63;
  const int w = tid >> 6;  // 0..7
  const int quarter = lane >> 4;
  const int c16 = lane & 15;
  const int blk = blockIdx.x;

  // ---- agg phase: wave w -> LDS rows w*4 .. w*4+3 ----
  for (int j = 0; j < 4; ++j) {
    const int row = w * 4 + j;
    const int node = blk * FROWS + row;
    float ox = 0.f, oy = 0.f, oz = 0.f, ow = 0.f;
    if (node < N_NODES)
      agg_core(hb_in, ss_in, sd_in, rowp, csr, node, lane, quarter, c16,
               do_elu, &lps[w][0], ox, oy, oz, ow);
    if (quarter == 0) {
      float4 o4 = {ox, oy, oz, ow};
      *(float4*)&outT[row][4 * c16] = o4;  // 16B-aligned: 4*(68*row+4c16)%16==0
    }
  }
  __syncthreads();

  // ---- gemm phase: wave w -> tile t=w>>2 (rows t*16..+15), cb=w&3 ----
  const int t = w >> 2;
  const int cb = w & 3;
  const int r16 = c16;
  const int g4 = quarter;

  bf16x8 Ah[2], Al[2];
#pragma unroll
  for (int ks = 0; ks < 2; ++ks) {
    const float* src = &outT[t * 16 + r16][32 * ks + 8 * g4];
    float4 f0 = *(const float4*)src;
    float4 f1 = *(const float4*)(src + 4);
    float v[8] = {f0.x, f0.y, f0.z, f0.w, f1.x, f1.y, f1.z, f1.w};
#pragma unroll
    for (int jj = 0; jj < 8; ++jj) {
      unsigned short hu = f2bf(v[jj]);
      Ah[ks][jj] = (short)hu;
      Al[ks][jj] = (short)f2bf(v[jj] - bf2f(hu));
    }
  }

  const bf16x8* WH = (const bf16x8*)wfH;
  const bf16x8* WL = (const bf16x8*)wfL;
  f32x4 acc = (f32x4){0.f, 0.f, 0.f, 0.f};
#pragma unroll
  for (int ks = 0; ks < 2; ++ks) {
    int fi = ((mat * 4 + cb) * 2 + ks) * 64 + lane;
    bf16x8 Bh = WH[fi];
    bf16x8 Bl = WL[fi];
    acc = __builtin_amdgcn_mfma_f32_16x16x32_bf16(Ah[ks], Bh, acc, 0, 0, 0);
    acc = __builtin_amdgcn_mfma_f32_16x16x32_bf16(Al[ks], Bh, acc, 0, 0, 0);
    acc = __builtin_amdgcn_mfma_f32_16x16x32_bf16(Ah[ks], Bl, acc, 0, 0, 0);
  }
#pragma unroll
  for (int reg = 0; reg < 4; ++reg) {
    int row = blk * FROWS + t * 16 + 4 * g4 + reg;
    if (row < N_NODES) hb_out[row * DIM + cb * 16 + r16] = f2bf(acc[reg]);
  }

  if (cb == 0) {
    f32x4 acc2 = (f32x4){0.f, 0.f, 0.f, 0.f};
#pragma unroll
    for (int ks = 0; ks < 2; ++ks) {
      bf16x8 Ba = *(const bf16x8*)(baf + ((mat * 2 + ks) * 64 + lane) * 8);
      acc2 = __builtin_amdgcn_mfma_f32_16x16x32_bf16(Ah[ks], Ba, acc2, 0, 0, 0);
      acc2 = __builtin_amdgcn_mfma_f32_16x16x32_bf16(Al[ks], Ba, acc2, 0, 0, 0);
    }
#pragma unroll
    for (int reg = 0; reg < 4; ++reg) {
      float tmp = acc2[reg] + __shfl_xor(acc2[reg], 1);  // col pairs
      int row = blk * FROWS + t * 16 + 4 * g4 + reg;
      if (row < N_NODES) {
        if (r16 == 0) ss_out[row] = tmp;
        else if (r16 == 2) sd_out[row] = tmp;
      }
    }
  }
}

// ---------- final-layer agg (R5-verified single-node; is_final path) ----------
__global__ __launch_bounds__(256) void k_agg(
    const unsigned short* __restrict__ hb, const float* __restrict__ ss,
    const float* __restrict__ sd, const int* __restrict__ rowp,
    const int* __restrict__ csr, void* __restrict__ out_final,
    const int* __restrict__ flags, int do_elu) {
  __shared__ __align__(16) int2 lps[4][64];
  const int lane = threadIdx.x & 63;
  const int quarter = lane >> 4;
  const int c16 = lane & 15;
  const int w = threadIdx.x >> 6;
  const int node = blockIdx.x * 4 + w;
  float ox, oy, oz, ow;
  agg_core(hb, ss, sd, rowp, csr, node, lane, quarter, c16, do_elu,
           &lps[w][0], ox, oy, oz, ow);
  if (quarter == 0) {
    int idx = node * DIM + 4 * c16;
    if (flags[0]) {
      ushort4 o4 = {f2bf(ox), f2bf(oy), f2bf(oz), f2bf(ow)};
      *(ushort4*)((unsigned short*)out_final + idx) = o4;
    } else {
      float4 o4 = {ox, oy, oz, ow};
      *(float4*)((float*)out_final + idx) = o4;
    }
  }
}

// ---------- launch ----------
extern "C" void kernel_launch(void* const* d_in, const int* in_sizes, int n_in,
                              void* d_out, int out_size, void* d_ws, size_t ws_size,
                              hipStream_t stream) {
  const void* feat = d_in[0];
  const int* eidx = (const int*)d_in[1];

  unsigned short* xh1 = (unsigned short*)d_ws;          // N*64 bf16 (layer-0 hi)
  unsigned short* xl1 = xh1 + N_NODES * DIM;            // N*64 bf16 (layer-0 lo)
  unsigned short* hbA = xl1 + N_NODES * DIM;            // N*64 bf16
  unsigned short* hbB = hbA + N_NODES * DIM;            // N*64 bf16
  unsigned short* wfH = hbB + N_NODES * DIM;            // 32768
  unsigned short* wfL = wfH + 32768;                    // 32768
  unsigned short* baf = wfL + 32768;                    // 8192
  int2* ebuf = (int2*)(baf + 8192);                     // E int2
  float* ssA = (float*)(ebuf + N_EDGES);                // N
  float* sdA = ssA + N_NODES;                           // N
  float* ssB = sdA + N_NODES;                           // N
  float* sdB = ssB + N_NODES;                           // N
  int* csr  = (int*)(sdB + N_NODES);                    // E
  int* hist = csr + N_EDGES;                            // NB*NBLK
  int* hscan = hist + NB * NBLK;                        // NB*NBLK
  int* bsum = hscan + NB * NBLK;                        // 256
  int* rowp = bsum + 256;                               // N+1
  int* flags = rowp + N_NODES + 1;                      // 2

  const int NH = NB * NBLK;                 // 50048
  const int SBH = (NH + 255) / 256;         // 196

  k_detect<<<1, 64, 0, stream>>>((const unsigned short*)feat,
                                 (const unsigned int*)eidx, flags);
  k_wprep<<<8, 256, 0, stream>>>(d_in[2], d_in[3], d_in[4],
                                 d_in[5], d_in[6], d_in[7],
                                 flags, wfH, wfL, baf);
  k_split<<<(N_NODES * DIM / 4 + 255) / 256, 256, 0, stream>>>(feat, flags, xh1, xl1);
  k_hist1<<<NBLK, 256, 0, stream>>>(eidx, flags, hist);
  k_scan1<<<SBH, 256, 0, stream>>>(hist, hscan, bsum, NH);
  k_scan2<<<1, 256, 0, stream>>>(bsum, SBH);
  k_scan3<<<SBH, 256, 0, stream>>>(hscan, bsum, NH);
  k_scatter<<<NBLK, 256, 0, stream>>>(eidx, flags, hscan, ebuf);
  k_place<<<NB, 256, 0, stream>>>(ebuf, hscan, rowp, csr);

  const int GB = (2 * NTILES + 3) / 4;              // layer-0 gemm
  const int FB = (N_NODES + FROWS - 1) / FROWS;     // 1563 fused blocks

  // layer 0 gemm: features -> hbA, ssA, sdA
  k_gemm<<<GB, 256, 0, stream>>>(xh1, xl1, wfH, wfL, baf, 0, hbA, ssA, sdA);

  // 7 fused layers: agg(k) + gemm(k+1). X_0 = A; alternate.
  for (int k = 0; k < 7; ++k) {
    const unsigned short* hin = (k & 1) ? hbB : hbA;
    const float* sin_ = (k & 1) ? ssB : ssA;
    const float* din = (k & 1) ? sdB : sdA;
    unsigned short* hout = (k & 1) ? hbA : hbB;
    float* sout = (k & 1) ? ssA : ssB;
    float* dout = (k & 1) ? sdA : sdB;
    k_fused<<<FB, 512, 0, stream>>>(hin, sin_, din, rowp, csr, wfH, wfL, baf,
                                    k + 1, (k == 3) ? 1 : 0, hout, sout, dout);
  }

  // final agg (layer 7): X_7 = B (7 fused flips from A)
  k_agg<<<N_NODES / 4, 256, 0, stream>>>(hbB, ssB, sdB, rowp, csr, d_out,
                                         flags, 1);
}

// Round 12
// 347.924 us; speedup vs baseline: 14.2060x; 1.0456x over previous
//
#include <hip/hip_runtime.h>
#include <hip/hip_bf16.h>

#define N_NODES 50000
#define N_EDGES 800000
#define DIM 64
#define NB 391      // dst buckets of 128 nodes: ceil(50000/128)
#define NBLK 128    // blocks in bucketize pass
#define CHUNK 6250  // N_EDGES / NBLK (exact)
#define CAP 4096    // LDS staging capacity per bucket segment (avg ~2048)
#define NTILES 3125 // 50000 / 16 row-tiles (exact)
#define FROWS 32    // fused kernel: rows (nodes) per block
#define FPAD 68     // LDS row stride (floats): 16B-aligned, 68%32=4 -> 2-way banks

typedef __attribute__((ext_vector_type(8))) short bf16x8;
typedef __attribute__((ext_vector_type(4))) float f32x4;

// ---------- helpers ----------
__device__ __forceinline__ float bf2f(unsigned short u) {
  return __uint_as_float(((unsigned int)u) << 16);
}
__device__ __forceinline__ unsigned short f2bf(float f) {
  unsigned int x = __float_as_uint(f);
  unsigned int r = (x + 0x7fffu + ((x >> 16) & 1u)) >> 16;  // RNE
  return (unsigned short)r;
}

// ---------- dtype detection (flags[0]=bf16 inputs, flags[1]=int64 indices) ----------
__global__ void k_detect(const unsigned short* __restrict__ feat,
                         const unsigned int* __restrict__ eidx,
                         int* __restrict__ flags) {
  int lane = threadIdx.x;  // 64 threads
  float v = bf2f(feat[2 * lane]);
  bool big = !(fabsf(v) < 1000.0f);
  unsigned long long bb = __ballot(big);
  unsigned int w = eidx[2 * lane + 1];
  unsigned long long bz = __ballot(w == 0u);
  if (lane == 0) {
    flags[0] = (__popcll(bb) < 8) ? 1 : 0;
    flags[1] = (__popcll(bz) == 64) ? 1 : 0;
  }
}

__device__ __forceinline__ int eidx_at(const int* __restrict__ p, int k, int i64) {
  return p[i64 ? (k << 1) : k];
}

// ---------- one-time fragment prep (R12, verified) ----------
__global__ __launch_bounds__(256) void k_wprep(
    const void* __restrict__ W1, const void* __restrict__ A1s,
    const void* __restrict__ A1d, const void* __restrict__ W2,
    const void* __restrict__ A2s, const void* __restrict__ A2d,
    const int* __restrict__ flags, unsigned short* __restrict__ wfH,
    unsigned short* __restrict__ wfL, unsigned short* __restrict__ baf) {
  __shared__ float Wsh[DIM * DIM];
  __shared__ float was[DIM], wad[DIM];
  const int b = blockIdx.x;  // head-matrix 0..7
  const int t = threadIdx.x;
  const int bf = flags[0];
  const void* Wv = (b < 4) ? W1 : W2;
  const void* av = (b < 4) ? A1s : A2s;
  const void* dv = (b < 4) ? A1d : A2d;
  const int hm = (b < 4) ? b : b - 4;
  for (int i = t; i < DIM * DIM; i += 256)
    Wsh[i] = bf ? bf2f(((const unsigned short*)Wv)[hm * DIM * DIM + i])
                : ((const float*)Wv)[hm * DIM * DIM + i];
  __syncthreads();
  if (t < 128) {
    int k = t & 63, isd = t >> 6;
    const void* aptr = isd ? dv : av;
    float acc = 0.f;
    for (int c = 0; c < DIM; ++c) {
      float a = bf ? bf2f(((const unsigned short*)aptr)[hm * DIM + c])
                   : ((const float*)aptr)[hm * DIM + c];
      acc = fmaf(Wsh[k * DIM + c], a, acc);
    }
    (isd ? wad : was)[k] = acc;
  }
  __syncthreads();
  // W fragments: value at (cb,ks,lane,j) = W[(32ks+8g4+j)*64 + 16cb+r16]
  for (int idx = t; idx < 512; idx += 256) {
    int lane = idx & 63, ks = (idx >> 6) & 1, cb = idx >> 7;
    int g4 = lane >> 4, r16 = lane & 15;
    int fo = (((b * 4 + cb) * 2 + ks) * 64 + lane) * 8;
#pragma unroll
    for (int j = 0; j < 8; ++j) {
      int k = 32 * ks + 8 * g4 + j;
      float w = Wsh[k * DIM + 16 * cb + r16];
      unsigned short hu = f2bf(w);
      wfH[fo + j] = hu;
      wfL[fo + j] = f2bf(w - bf2f(hu));
    }
  }
  // score fragments
  for (int idx = t; idx < 128; idx += 256) {
    int lane = idx & 63, ks = idx >> 6;
    int g4 = lane >> 4, r16 = lane & 15;
    int fo = ((b * 2 + ks) * 64 + lane) * 8;
#pragma unroll
    for (int j = 0; j < 8; ++j) {
      int k = 32 * ks + 8 * g4 + j;
      unsigned short u = 0;
      if (r16 < 4) {
        float w_ = (r16 < 2) ? was[k] : wad[k];
        unsigned short uh = f2bf(w_);
        u = (r16 & 1) ? f2bf(w_ - bf2f(uh)) : uh;
      }
      baf[fo + j] = u;
    }
  }
}

// ---------- generalized scan (n <= 65536) ----------
__global__ void k_scan1(const int* __restrict__ in, int* __restrict__ out,
                        int* __restrict__ bsum, int n) {
  __shared__ int sm[256];
  int t = threadIdx.x, b = blockIdx.x, i = b * 256 + t;
  int v = (i < n) ? in[i] : 0;
  sm[t] = v;
  __syncthreads();
  for (int off = 1; off < 256; off <<= 1) {
    int x = (t >= off) ? sm[t - off] : 0;
    __syncthreads();
    sm[t] += x;
    __syncthreads();
  }
  if (i < n) out[i] = sm[t] - v;
  if (t == 255) bsum[b] = sm[t];
}

__global__ void k_scan2(int* __restrict__ bsum, int nb) {
  __shared__ int sm[256];
  int t = threadIdx.x;
  int v = (t < nb) ? bsum[t] : 0;
  sm[t] = v;
  __syncthreads();
  for (int off = 1; off < 256; off <<= 1) {
    int x = (t >= off) ? sm[t - off] : 0;
    __syncthreads();
    sm[t] += x;
    __syncthreads();
  }
  if (t < nb) bsum[t] = sm[t] - v;
}

__global__ void k_scan3(int* __restrict__ out, const int* __restrict__ bsum, int n) {
  int t = threadIdx.x, b = blockIdx.x, i = b * 256 + t;
  if (i < n) out[i] += bsum[b];
}

// ---------- bucketed CSR build ----------
__global__ __launch_bounds__(256) void k_hist1(const int* __restrict__ eidx,
                                               const int* __restrict__ flags,
                                               int* __restrict__ hist) {
  __shared__ int h[NB];
  int t = threadIdx.x, b = blockIdx.x;
  for (int i = t; i < NB; i += 256) h[i] = 0;
  __syncthreads();
  int i64 = flags[1];
  int lo = b * CHUNK;
  for (int i = t; i < CHUNK; i += 256) {
    int d = eidx_at(eidx, N_EDGES + lo + i, i64);
    atomicAdd(&h[d >> 7], 1);
  }
  __syncthreads();
  for (int i = t; i < NB; i += 256) hist[i * NBLK + b] = h[i];
}

__global__ __launch_bounds__(256) void k_scatter(const int* __restrict__ eidx,
                                                 const int* __restrict__ flags,
                                                 const int* __restrict__ hscan,
                                                 int2* __restrict__ ebuf) {
  __shared__ int cur[NB];
  int t = threadIdx.x, b = blockIdx.x;
  for (int i = t; i < NB; i += 256) cur[i] = hscan[i * NBLK + b];
  __syncthreads();
  int i64 = flags[1];
  int lo = b * CHUNK;
  for (int i = t; i < CHUNK; i += 256) {
    int d = eidx_at(eidx, N_EDGES + lo + i, i64);
    int s = eidx_at(eidx, lo + i, i64);
    int pos = atomicAdd(&cur[d >> 7], 1);
    ebuf[pos] = make_int2(s, d);
  }
}

__global__ __launch_bounds__(256) void k_place(const int2* __restrict__ ebuf,
                                               const int* __restrict__ hscan,
                                               int* __restrict__ rowp,
                                               int* __restrict__ csr) {
  __shared__ int hcnt[128];
  __shared__ int sm[128];
  __shared__ int cur[128];
  __shared__ int lcsr[CAP];
  int t = threadIdx.x, b = blockIdx.x;
  int lo = hscan[b * NBLK];
  int hi = (b + 1 < NB) ? hscan[(b + 1) * NBLK] : N_EDGES;
  if (t < 128) hcnt[t] = 0;
  __syncthreads();
  for (int i = lo + t; i < hi; i += 256) atomicAdd(&hcnt[ebuf[i].y & 127], 1);
  __syncthreads();
  int v = (t < 128) ? hcnt[t] : 0;
  if (t < 128) sm[t] = v;
  __syncthreads();
  for (int off = 1; off < 128; off <<= 1) {
    int x = (t < 128 && t >= off) ? sm[t - off] : 0;
    __syncthreads();
    if (t < 128) sm[t] += x;
    __syncthreads();
  }
  int d0 = b * 128;
  if (t < 128) {
    int excl = sm[t] - v;  // exclusive local prefix
    cur[t] = excl;
    int d = d0 + t;
    if (d < N_NODES) rowp[d] = lo + excl;
  }
  if (b == NB - 1 && t == 0) rowp[N_NODES] = N_EDGES;
  __syncthreads();
  int seg_sz = hi - lo;
  if (seg_sz <= CAP) {
    for (int i = lo + t; i < hi; i += 256) {
      int2 pr = ebuf[i];
      int pos = atomicAdd(&cur[pr.y & 127], 1);
      lcsr[pos] = pr.x;
    }
    __syncthreads();
    for (int i = t; i < seg_sz; i += 256) csr[lo + i] = lcsr[i];
  } else {  // overflow fallback
    for (int i = lo + t; i < hi; i += 256) {
      int2 pr = ebuf[i];
      int pos = atomicAdd(&cur[pr.y & 127], 1);
      csr[lo + pos] = pr.x;
    }
  }
}

// ---------- MFMA h = x@W, layer 0 only (R15: direct feat read, R4-verified
// in-register hi/lo split — removes k_split + xh/xl round-trip) ----------
__global__ __launch_bounds__(256) void k_gemm(
    const void* __restrict__ xv,
    const unsigned short* __restrict__ wfH, const unsigned short* __restrict__ wfL,
    const unsigned short* __restrict__ baf, int mat,
    const int* __restrict__ flags, unsigned short* __restrict__ hb,
    float* __restrict__ ss, float* __restrict__ sd) {
  const int bf = flags[0];
  const int lane = threadIdx.x & 63;
  const int w = blockIdx.x * 4 + (threadIdx.x >> 6);
  const int wtile = w >> 1;
  if (wtile >= NTILES) return;
  const int cbh = (w & 1) * 2;  // col-blocks {cbh, cbh+1}
  const int r16 = lane & 15;
  const int g4 = lane >> 4;
  const int row0 = wtile * 16;

  const bf16x8* WH = (const bf16x8*)wfH;
  const bf16x8* WL = (const bf16x8*)wfL;
  bf16x8 Bh[2][2], Bl[2][2];
#pragma unroll
  for (int c = 0; c < 2; ++c)
#pragma unroll
    for (int ks = 0; ks < 2; ++ks) {
      int fi = ((mat * 4 + cbh + c) * 2 + ks) * 64 + lane;
      Bh[c][ks] = WH[fi];
      Bl[c][ks] = WL[fi];
    }

  bf16x8 Ah[2], Al[2];
  if (bf) {
    const unsigned short* xp = (const unsigned short*)xv + (row0 + r16) * DIM + 8 * g4;
#pragma unroll
    for (int ks = 0; ks < 2; ++ks) Ah[ks] = *(const bf16x8*)(xp + 32 * ks);
  } else {
    const float* xp = (const float*)xv + (row0 + r16) * DIM + 8 * g4;
#pragma unroll
    for (int ks = 0; ks < 2; ++ks) {
      float4 f0 = *(const float4*)(xp + 32 * ks);
      float4 f1 = *(const float4*)(xp + 32 * ks + 4);
      float v[8] = {f0.x, f0.y, f0.z, f0.w, f1.x, f1.y, f1.z, f1.w};
#pragma unroll
      for (int j = 0; j < 8; ++j) {
        unsigned short hu = f2bf(v[j]);
        Ah[ks][j] = (short)hu;
        Al[ks][j] = (short)f2bf(v[j] - bf2f(hu));
      }
    }
  }

  f32x4 acc[2];
#pragma unroll
  for (int c = 0; c < 2; ++c) {
    acc[c] = (f32x4){0.f, 0.f, 0.f, 0.f};
#pragma unroll
    for (int ks = 0; ks < 2; ++ks) {
      acc[c] = __builtin_amdgcn_mfma_f32_16x16x32_bf16(Ah[ks], Bh[c][ks], acc[c], 0, 0, 0);
      if (!bf)
        acc[c] = __builtin_amdgcn_mfma_f32_16x16x32_bf16(Al[ks], Bh[c][ks], acc[c], 0, 0, 0);
      acc[c] = __builtin_amdgcn_mfma_f32_16x16x32_bf16(Ah[ks], Bl[c][ks], acc[c], 0, 0, 0);
    }
  }

#pragma unroll
  for (int c = 0; c < 2; ++c)
#pragma unroll
    for (int reg = 0; reg < 4; ++reg)
      hb[(row0 + 4 * g4 + reg) * DIM + (cbh + c) * 16 + r16] = f2bf(acc[c][reg]);

  if (cbh == 0) {
    f32x4 acc2 = (f32x4){0.f, 0.f, 0.f, 0.f};
#pragma unroll
    for (int ks = 0; ks < 2; ++ks) {
      bf16x8 Ba = *(const bf16x8*)(baf + ((mat * 2 + ks) * 64 + lane) * 8);
      acc2 = __builtin_amdgcn_mfma_f32_16x16x32_bf16(Ah[ks], Ba, acc2, 0, 0, 0);
      if (!bf)
        acc2 = __builtin_amdgcn_mfma_f32_16x16x32_bf16(Al[ks], Ba, acc2, 0, 0, 0);
    }
#pragma unroll
    for (int reg = 0; reg < 4; ++reg) {
      float tmp = acc2[reg] + __shfl_xor(acc2[reg], 1);  // col pairs (0,1)/(2,3)
      int row = row0 + 4 * g4 + reg;
      if (r16 == 0) ss[row] = tmp;
      else if (r16 == 2) sd[row] = tmp;
    }
  }
}

// ---------- shared agg pieces (R5-verified) ----------
__device__ __forceinline__ void quad_accum(const unsigned short* __restrict__ hb,
                                           const int2* __restrict__ lps, int cl,
                                           int quarter, int c16, float4& acc) {
  const int quads = (cl + 3) >> 2;
#pragma unroll 4
  for (int tt = 0; tt < quads; ++tt) {
    int j = 4 * tt + quarter;  // tail entries have p=0,s=0 -> contribute 0
    int2 pv = lps[j];          // LDS broadcast within quarter-wave
    float pj = __int_as_float(pv.x);
    int sj = pv.y;
    ushort4 hv = *(const ushort4*)(hb + sj * DIM + 4 * c16);
    acc.x = fmaf(pj, bf2f(hv.x), acc.x);
    acc.y = fmaf(pj, bf2f(hv.y), acc.y);
    acc.z = fmaf(pj, bf2f(hv.z), acc.z);
    acc.w = fmaf(pj, bf2f(hv.w), acc.w);
  }
}

__device__ __forceinline__ void agg_node_big(
    const unsigned short* __restrict__ hb, const float* __restrict__ ss,
    float sdn, int base, int deg, const int* __restrict__ csr, int lane,
    int quarter, int c16, int2* __restrict__ lpw, float4& acc, float& zo) {
  float z = 0.f;
  for (int c = 0; c < deg; c += 64) {
    int j = c + lane;
    float p = 0.f; int s = 0;
    if (j < deg) {
      s = csr[base + j];
      float sc = ss[s] + sdn;
      sc = (sc >= 0.f) ? sc : 0.2f * sc;
      p = __expf(sc);
    }
    lpw[lane] = make_int2(__float_as_int(p), s);
    __builtin_amdgcn_wave_barrier();
    z += p;
    const int cl = (deg - c < 64) ? (deg - c) : 64;
    quad_accum(hb, lpw, cl, quarter, c16, acc);
    __builtin_amdgcn_wave_barrier();
  }
#pragma unroll
  for (int off = 32; off > 0; off >>= 1) z += __shfl_xor(z, off);
  zo = z;
}

// computes softmax-weighted aggregate for `node` into (ox..ow) on all lanes
// (lane's c16 selects cols 4c16..4c16+3). elu applied if do_elu.
__device__ __forceinline__ void agg_core(
    const unsigned short* __restrict__ hb, const float* __restrict__ ss,
    const float* __restrict__ sd, const int* __restrict__ rowp,
    const int* __restrict__ csr, int node, int lane, int quarter, int c16,
    int do_elu, int2* __restrict__ lpw, float& ox, float& oy, float& oz,
    float& ow) {
  const int base = rowp[node];
  const int deg = rowp[node + 1] - base;
  const float sdn = sd[node];
  float4 acc = {0.f, 0.f, 0.f, 0.f};
  float z;
  if (deg <= 64) {
    int s = 0;
    float p = 0.f;
    if (lane < deg) {
      s = csr[base + lane];
      float t = ss[s] + sdn;
      t = (t >= 0.f) ? t : 0.2f * t;
      p = __expf(t);  // shift-invariant softmax, scores O(10)
    }
    lpw[lane] = make_int2(__float_as_int(p), s);
    z = p;
    __builtin_amdgcn_wave_barrier();
    quad_accum(hb, lpw, deg, quarter, c16, acc);
    __builtin_amdgcn_wave_barrier();  // lpw reused by caller's next node
#pragma unroll
    for (int off = 32; off > 0; off >>= 1) z += __shfl_xor(z, off);
  } else {
    agg_node_big(hb, ss, sdn, base, deg, csr, lane, quarter, c16, lpw, acc, z);
  }
  acc.x += __shfl_xor(acc.x, 16);
  acc.y += __shfl_xor(acc.y, 16);
  acc.z += __shfl_xor(acc.z, 16);
  acc.w += __shfl_xor(acc.w, 16);
  acc.x += __shfl_xor(acc.x, 32);
  acc.y += __shfl_xor(acc.y, 32);
  acc.z += __shfl_xor(acc.z, 32);
  acc.w += __shfl_xor(acc.w, 32);
  float inv = 1.f / (z + 1e-16f);
  ox = acc.x * inv; oy = acc.y * inv;
  oz = acc.z * inv; ow = acc.w * inv;
  if (do_elu) {
    ox = (ox > 0.f) ? ox : expm1f(ox);
    oy = (oy > 0.f) ? oy : expm1f(oy);
    oz = (oz > 0.f) ? oz : expm1f(oz);
    ow = (ow > 0.f) ? ow : expm1f(ow);
  }
}

// ---------- R15: fused agg->gemm with BATCHED phase-1 across the wave's 4 nodes ----------
// The R14 serial 4-node loop stacked four ~2000cy dependent chains
// (rowp->csr->ss->exp->LDS->gathers) per wave. Batching phase 1 issues the 4
// csr loads and 4 ss gathers independently (one chain instead of four), then
// runs the 4 gather loops back-to-back. Per-node arithmetic order unchanged.
__global__ __launch_bounds__(512) void k_fused(
    const unsigned short* __restrict__ hb_in, const float* __restrict__ ss_in,
    const float* __restrict__ sd_in, const int* __restrict__ rowp,
    const int* __restrict__ csr, const unsigned short* __restrict__ wfH,
    const unsigned short* __restrict__ wfL, const unsigned short* __restrict__ baf,
    int mat, int do_elu, unsigned short* __restrict__ hb_out,
    float* __restrict__ ss_out, float* __restrict__ sd_out) {
  __shared__ float outT[FROWS][FPAD];
  __shared__ __align__(16) int2 lps[8][4][64];  // per wave: 4 node buffers (16 KB)
  const int tid = threadIdx.x;
  const int lane = tid & 63;
  const int w = tid >> 6;  // 0..7
  const int quarter = lane >> 4;
  const int c16 = lane & 15;
  const int blk = blockIdx.x;
  const int node0 = blk * FROWS + w * 4;

  // wave-uniform row pointers (clamped: OOB nodes get deg 0)
  int bp[5];
#pragma unroll
  for (int j = 0; j < 5; ++j) {
    int idx = node0 + j;
    bp[j] = rowp[(idx < N_NODES) ? idx : N_NODES];
  }
  int deg[4];
  float sdn[4];
#pragma unroll
  for (int j = 0; j < 4; ++j) {
    deg[j] = bp[j + 1] - bp[j];
    int idx = node0 + j;
    sdn[j] = sd_in[(idx < N_NODES) ? idx : (N_NODES - 1)];
  }

  if (deg[0] <= 64 && deg[1] <= 64 && deg[2] <= 64 && deg[3] <= 64) {
    // ---- batched phase 1: 4 independent csr loads, then 4 independent ss gathers
    int s4[4];
    float p4[4];
#pragma unroll
    for (int j = 0; j < 4; ++j)
      s4[j] = (lane < deg[j]) ? csr[bp[j] + lane] : 0;
#pragma unroll
    for (int j = 0; j < 4; ++j) {
      float t = ss_in[s4[j]] + sdn[j];
      t = (t >= 0.f) ? t : 0.2f * t;
      p4[j] = (lane < deg[j]) ? __expf(t) : 0.f;
    }
#pragma unroll
    for (int j = 0; j < 4; ++j)
      lps[w][j][lane] = make_int2(__float_as_int(p4[j]), s4[j]);
    __builtin_amdgcn_wave_barrier();

    // ---- 4 gather loops (independent; iterations pipeline)
    float4 acc[4];
#pragma unroll
    for (int j = 0; j < 4; ++j) acc[j] = (float4){0.f, 0.f, 0.f, 0.f};
#pragma unroll
    for (int j = 0; j < 4; ++j)
      quad_accum(hb_in, &lps[w][j][0], deg[j], quarter, c16, acc[j]);

    // ---- z reductions + epilogues
#pragma unroll
    for (int j = 0; j < 4; ++j) {
      float z = p4[j];
#pragma unroll
      for (int off = 32; off > 0; off >>= 1) z += __shfl_xor(z, off);
      float4 a = acc[j];
      a.x += __shfl_xor(a.x, 16);
      a.y += __shfl_xor(a.y, 16);
      a.z += __shfl_xor(a.z, 16);
      a.w += __shfl_xor(a.w, 16);
      a.x += __shfl_xor(a.x, 32);
      a.y += __shfl_xor(a.y, 32);
      a.z += __shfl_xor(a.z, 32);
      a.w += __shfl_xor(a.w, 32);
      float inv = 1.f / (z + 1e-16f);
      float ox = a.x * inv, oy = a.y * inv, oz = a.z * inv, ow = a.w * inv;
      if (do_elu) {
        ox = (ox > 0.f) ? ox : expm1f(ox);
        oy = (oy > 0.f) ? oy : expm1f(oy);
        oz = (oz > 0.f) ? oz : expm1f(oz);
        ow = (ow > 0.f) ? ow : expm1f(ow);
      }
      if (quarter == 0) {
        float4 o4 = {ox, oy, oz, ow};
        *(float4*)&outT[w * 4 + j][4 * c16] = o4;  // 16B-aligned
      }
    }
  } else {
    // rare path: verified per-node serial agg
    for (int j = 0; j < 4; ++j) {
      const int row = w * 4 + j;
      const int node = node0 + j;
      float ox = 0.f, oy = 0.f, oz = 0.f, ow = 0.f;
      if (node < N_NODES)
        agg_core(hb_in, ss_in, sd_in, rowp, csr, node, lane, quarter, c16,
                 do_elu, &lps[w][j][0], ox, oy, oz, ow);
      if (quarter == 0) {
        float4 o4 = {ox, oy, oz, ow};
        *(float4*)&outT[row][4 * c16] = o4;
      }
    }
  }
  __syncthreads();

  // ---- gemm phase: wave w -> tile t=w>>2 (rows t*16..+15), cb=w&3 ----
  const int t = w >> 2;
  const int cb = w & 3;
  const int r16 = c16;
  const int g4 = quarter;

  bf16x8 Ah[2], Al[2];
#pragma unroll
  for (int ks = 0; ks < 2; ++ks) {
    const float* src = &outT[t * 16 + r16][32 * ks + 8 * g4];
    float4 f0 = *(const float4*)src;
    float4 f1 = *(const float4*)(src + 4);
    float v[8] = {f0.x, f0.y, f0.z, f0.w, f1.x, f1.y, f1.z, f1.w};
#pragma unroll
    for (int jj = 0; jj < 8; ++jj) {
      unsigned short hu = f2bf(v[jj]);
      Ah[ks][jj] = (short)hu;
      Al[ks][jj] = (short)f2bf(v[jj] - bf2f(hu));
    }
  }

  const bf16x8* WH = (const bf16x8*)wfH;
  const bf16x8* WL = (const bf16x8*)wfL;
  f32x4 acc2 = (f32x4){0.f, 0.f, 0.f, 0.f};
#pragma unroll
  for (int ks = 0; ks < 2; ++ks) {
    int fi = ((mat * 4 + cb) * 2 + ks) * 64 + lane;
    bf16x8 Bh = WH[fi];
    bf16x8 Bl = WL[fi];
    acc2 = __builtin_amdgcn_mfma_f32_16x16x32_bf16(Ah[ks], Bh, acc2, 0, 0, 0);
    acc2 = __builtin_amdgcn_mfma_f32_16x16x32_bf16(Al[ks], Bh, acc2, 0, 0, 0);
    acc2 = __builtin_amdgcn_mfma_f32_16x16x32_bf16(Ah[ks], Bl, acc2, 0, 0, 0);
  }
#pragma unroll
  for (int reg = 0; reg < 4; ++reg) {
    int row = blk * FROWS + t * 16 + 4 * g4 + reg;
    if (row < N_NODES) hb_out[row * DIM + cb * 16 + r16] = f2bf(acc2[reg]);
  }

  if (cb == 0) {
    f32x4 accs = (f32x4){0.f, 0.f, 0.f, 0.f};
#pragma unroll
    for (int ks = 0; ks < 2; ++ks) {
      bf16x8 Ba = *(const bf16x8*)(baf + ((mat * 2 + ks) * 64 + lane) * 8);
      accs = __builtin_amdgcn_mfma_f32_16x16x32_bf16(Ah[ks], Ba, accs, 0, 0, 0);
      accs = __builtin_amdgcn_mfma_f32_16x16x32_bf16(Al[ks], Ba, accs, 0, 0, 0);
    }
#pragma unroll
    for (int reg = 0; reg < 4; ++reg) {
      float tmp = accs[reg] + __shfl_xor(accs[reg], 1);  // col pairs
      int row = blk * FROWS + t * 16 + 4 * g4 + reg;
      if (row < N_NODES) {
        if (r16 == 0) ss_out[row] = tmp;
        else if (r16 == 2) sd_out[row] = tmp;
      }
    }
  }
}

// ---------- final-layer agg (R5-verified single-node; is_final path) ----------
__global__ __launch_bounds__(256) void k_agg(
    const unsigned short* __restrict__ hb, const float* __restrict__ ss,
    const float* __restrict__ sd, const int* __restrict__ rowp,
    const int* __restrict__ csr, void* __restrict__ out_final,
    const int* __restrict__ flags, int do_elu) {
  __shared__ __align__(16) int2 lps[4][64];
  const int lane = threadIdx.x & 63;
  const int quarter = lane >> 4;
  const int c16 = lane & 15;
  const int w = threadIdx.x >> 6;
  const int node = blockIdx.x * 4 + w;
  float ox, oy, oz, ow;
  agg_core(hb, ss, sd, rowp, csr, node, lane, quarter, c16, do_elu,
           &lps[w][0], ox, oy, oz, ow);
  if (quarter == 0) {
    int idx = node * DIM + 4 * c16;
    if (flags[0]) {
      ushort4 o4 = {f2bf(ox), f2bf(oy), f2bf(oz), f2bf(ow)};
      *(ushort4*)((unsigned short*)out_final + idx) = o4;
    } else {
      float4 o4 = {ox, oy, oz, ow};
      *(float4*)((float*)out_final + idx) = o4;
    }
  }
}

// ---------- launch ----------
extern "C" void kernel_launch(void* const* d_in, const int* in_sizes, int n_in,
                              void* d_out, int out_size, void* d_ws, size_t ws_size,
                              hipStream_t stream) {
  const void* feat = d_in[0];
  const int* eidx = (const int*)d_in[1];

  unsigned short* hbA = (unsigned short*)d_ws;          // N*64 bf16
  unsigned short* hbB = hbA + N_NODES * DIM;            // N*64 bf16
  unsigned short* wfH = hbB + N_NODES * DIM;            // 32768
  unsigned short* wfL = wfH + 32768;                    // 32768
  unsigned short* baf = wfL + 32768;                    // 8192
  int2* ebuf = (int2*)(baf + 8192);                     // E int2
  float* ssA = (float*)(ebuf + N_EDGES);                // N
  float* sdA = ssA + N_NODES;                           // N
  float* ssB = sdA + N_NODES;                           // N
  float* sdB = ssB + N_NODES;                           // N
  int* csr  = (int*)(sdB + N_NODES);                    // E
  int* hist = csr + N_EDGES;                            // NB*NBLK
  int* hscan = hist + NB * NBLK;                        // NB*NBLK
  int* bsum = hscan + NB * NBLK;                        // 256
  int* rowp = bsum + 256;                               // N+1
  int* flags = rowp + N_NODES + 1;                      // 2

  const int NH = NB * NBLK;                 // 50048
  const int SBH = (NH + 255) / 256;         // 196

  k_detect<<<1, 64, 0, stream>>>((const unsigned short*)feat,
                                 (const unsigned int*)eidx, flags);
  k_wprep<<<8, 256, 0, stream>>>(d_in[2], d_in[3], d_in[4],
                                 d_in[5], d_in[6], d_in[7],
                                 flags, wfH, wfL, baf);
  k_hist1<<<NBLK, 256, 0, stream>>>(eidx, flags, hist);
  k_scan1<<<SBH, 256, 0, stream>>>(hist, hscan, bsum, NH);
  k_scan2<<<1, 256, 0, stream>>>(bsum, SBH);
  k_scan3<<<SBH, 256, 0, stream>>>(hscan, bsum, NH);
  k_scatter<<<NBLK, 256, 0, stream>>>(eidx, flags, hscan, ebuf);
  k_place<<<NB, 256, 0, stream>>>(ebuf, hscan, rowp, csr);

  const int GB = (2 * NTILES + 3) / 4;              // layer-0 gemm
  const int FB = (N_NODES + FROWS - 1) / FROWS;     // 1563 fused blocks

  // layer 0 gemm: features -> hbA, ssA, sdA (direct feat read)
  k_gemm<<<GB, 256, 0, stream>>>(feat, wfH, wfL, baf, 0, flags, hbA, ssA, sdA);

  // 7 fused layers: agg(k) + gemm(k+1). X_0 = A; alternate.
  for (int k = 0; k < 7; ++k) {
    const unsigned short* hin = (k & 1) ? hbB : hbA;
    const float* sin_ = (k & 1) ? ssB : ssA;
    const float* din = (k & 1) ? sdB : sdA;
    unsigned short* hout = (k & 1) ? hbA : hbB;
    float* sout = (k & 1) ? ssA : ssB;
    float* dout = (k & 1) ? sdA : sdB;
    k_fused<<<FB, 512, 0, stream>>>(hin, sin_, din, rowp, csr, wfH, wfL, baf,
                                    k + 1, (k == 3) ? 1 : 0, hout, sout, dout);
  }

  // final agg (layer 7): X_7 = B (7 fused flips from A)
  k_agg<<<N_NODES / 4, 256, 0, stream>>>(hbB, ssB, sdB, rowp, csr, d_out,
                                         flags, 1);
}